// Round 3
// baseline (1431.144 us; speedup 1.0000x reference)
//
#include <hip/hip_runtime.h>
#include <hip/hip_bf16.h>

#define NB 131072
#define MARGINF 1e-6f
#define WS_E2 16          // float index of e2[512]
#define WS_MASK 528       // float index of flag bitmask (4096 u32 words)
#define WS_MASKW 4096     // NB/32
#define WS_NEED ((WS_MASK + WS_MASKW) * 4)

// ws layout (bytes): [0,16) two doubles (vq_sum, rec_sum); [64,2112) e2[512] f32;
// [2112,18496) flag bitmask u32[4096]. Zeroed via hipMemsetAsync each call.

__global__ void prep_kernel(const float* __restrict__ emb, float* __restrict__ ws) {
    int t = blockIdx.x * 256 + threadIdx.x;
    if (t < 512) {
        const float* e = emb + (size_t)t * 128;
        float s0 = 0.f, s1 = 0.f, s2 = 0.f, s3 = 0.f;
        for (int d = 0; d < 128; d += 4) {
            s0 += e[d] * e[d];
            s1 += e[d + 1] * e[d + 1];
            s2 += e[d + 2] * e[d + 2];
            s3 += e[d + 3] * e[d + 3];
        }
        ws[WS_E2 + t] = (s0 + s1) + (s2 + s3);
    }
}

// Register-tiled GEMM step: out[j,r] for j in [0,256), r in [0,32).
// W is [256][IN] row-major (global), hin is LDS [IN][32], hout LDS [256][32].
static __device__ __forceinline__ void gemm_out256(
    const float* __restrict__ W, const float* __restrict__ bias, int IN,
    const float* __restrict__ hin, float* __restrict__ hout,
    float* __restrict__ WC, int t, int j0, int r0, bool do_relu)
{
    float acc[8][4];
#pragma unroll
    for (int a = 0; a < 8; ++a)
#pragma unroll
        for (int b = 0; b < 4; ++b) acc[a][b] = 0.f;

    float4 pa = *(const float4*)(W + (size_t)t * IN);
    float4 pb = *(const float4*)(W + (size_t)t * IN + 4);

    for (int i0 = 0; i0 < IN; i0 += 8) {
        __syncthreads();
        WC[0 * 256 + t] = pa.x; WC[1 * 256 + t] = pa.y;
        WC[2 * 256 + t] = pa.z; WC[3 * 256 + t] = pa.w;
        WC[4 * 256 + t] = pb.x; WC[5 * 256 + t] = pb.y;
        WC[6 * 256 + t] = pb.z; WC[7 * 256 + t] = pb.w;
        __syncthreads();
        if (i0 + 8 < IN) {
            pa = *(const float4*)(W + (size_t)t * IN + i0 + 8);
            pb = *(const float4*)(W + (size_t)t * IN + i0 + 12);
        }
#pragma unroll
        for (int i = 0; i < 8; ++i) {
            float4 w0 = *(const float4*)&WC[i * 256 + j0];
            float4 w1v = *(const float4*)&WC[i * 256 + j0 + 4];
            float4 h = *(const float4*)&hin[(i0 + i) * 32 + r0];
            float wv[8] = {w0.x, w0.y, w0.z, w0.w, w1v.x, w1v.y, w1v.z, w1v.w};
            float hv[4] = {h.x, h.y, h.z, h.w};
#pragma unroll
            for (int a = 0; a < 8; ++a)
#pragma unroll
                for (int b = 0; b < 4; ++b) acc[a][b] += wv[a] * hv[b];
        }
    }
#pragma unroll
    for (int a = 0; a < 8; ++a) {
        float bj = bias[j0 + a];
#pragma unroll
        for (int b = 0; b < 4; ++b) {
            float v = acc[a][b] + bj;
            if (do_relu) v = fmaxf(v, 0.f);
            hout[(j0 + a) * 32 + r0 + b] = v;
        }
    }
    __syncthreads();
}

__global__ __launch_bounds__(256, 2) void vqvae_main(
    const float* __restrict__ action,
    const float* __restrict__ w1, const float* __restrict__ b1,
    const float* __restrict__ w2, const float* __restrict__ b2,
    const float* __restrict__ w3, const float* __restrict__ b3,
    const float* __restrict__ emb,
    const float* __restrict__ d1w, const float* __restrict__ d1b,
    const float* __restrict__ d2w, const float* __restrict__ d2b,
    const float* __restrict__ rw, const float* __restrict__ rb,
    float* __restrict__ out, float* __restrict__ ws)
{
    __shared__ float X[256 * 32];
    __shared__ float Y[256 * 32];
    __shared__ float WC[2048];
    __shared__ float AT[6 * 32];
    __shared__ int IDXR[32];
    __shared__ int FLAGR[32];
    __shared__ float RED[8];

    const int t = threadIdx.x;
    const int tx = t & 31, ty = t >> 5;
    const int j0 = tx * 8, r0 = ty * 4;
    const int row0 = blockIdx.x * 32;

    // ---- load action tile (coalesced), store transposed [i][r] ----
    if (t < 192) {
        int r = t / 6, i = t - r * 6;
        AT[i * 32 + r] = action[(size_t)row0 * 6 + t];
    }
    __syncthreads();

    // ---- enc1: 6 -> 256, relu, -> X ----
    {
#pragma unroll
        for (int i = 0; i < 6; ++i) WC[i * 256 + t] = w1[t * 6 + i];
        __syncthreads();
        float acc[8][4];
#pragma unroll
        for (int a = 0; a < 8; ++a)
#pragma unroll
            for (int b = 0; b < 4; ++b) acc[a][b] = 0.f;
#pragma unroll
        for (int i = 0; i < 6; ++i) {
            float4 w0 = *(const float4*)&WC[i * 256 + j0];
            float4 w1v = *(const float4*)&WC[i * 256 + j0 + 4];
            float4 h = *(const float4*)&AT[i * 32 + r0];
            float wv[8] = {w0.x, w0.y, w0.z, w0.w, w1v.x, w1v.y, w1v.z, w1v.w};
            float hv[4] = {h.x, h.y, h.z, h.w};
#pragma unroll
            for (int a = 0; a < 8; ++a)
#pragma unroll
                for (int b = 0; b < 4; ++b) acc[a][b] += wv[a] * hv[b];
        }
#pragma unroll
        for (int a = 0; a < 8; ++a) {
            float bj = b1[j0 + a];
#pragma unroll
            for (int b = 0; b < 4; ++b)
                X[(j0 + a) * 32 + r0 + b] = fmaxf(acc[a][b] + bj, 0.f);
        }
        __syncthreads();
    }

    // ---- enc2: 256 -> 256, relu, X -> Y ----
    gemm_out256(w2, b2, 256, X, Y, WC, t, j0, r0, true);

    // ---- mu: 256 -> 128 (no relu), Y -> X[0..128) ----
    {
        const int jm0 = tx * 4;
        float acc[4][4];
#pragma unroll
        for (int a = 0; a < 4; ++a)
#pragma unroll
            for (int b = 0; b < 4; ++b) acc[a][b] = 0.f;
        float4 pa, pb;
        if (t < 128) {
            pa = *(const float4*)(w3 + (size_t)t * 256);
            pb = *(const float4*)(w3 + (size_t)t * 256 + 4);
        }
        for (int i0 = 0; i0 < 256; i0 += 8) {
            __syncthreads();
            if (t < 128) {
                WC[0 * 128 + t] = pa.x; WC[1 * 128 + t] = pa.y;
                WC[2 * 128 + t] = pa.z; WC[3 * 128 + t] = pa.w;
                WC[4 * 128 + t] = pb.x; WC[5 * 128 + t] = pb.y;
                WC[6 * 128 + t] = pb.z; WC[7 * 128 + t] = pb.w;
            }
            __syncthreads();
            if (t < 128 && i0 + 8 < 256) {
                pa = *(const float4*)(w3 + (size_t)t * 256 + i0 + 8);
                pb = *(const float4*)(w3 + (size_t)t * 256 + i0 + 12);
            }
#pragma unroll
            for (int i = 0; i < 8; ++i) {
                float4 w0 = *(const float4*)&WC[i * 128 + jm0];
                float4 h = *(const float4*)&Y[(i0 + i) * 32 + r0];
                float wv[4] = {w0.x, w0.y, w0.z, w0.w};
                float hv[4] = {h.x, h.y, h.z, h.w};
#pragma unroll
                for (int a = 0; a < 4; ++a)
#pragma unroll
                    for (int b = 0; b < 4; ++b) acc[a][b] += wv[a] * hv[b];
            }
        }
#pragma unroll
        for (int a = 0; a < 4; ++a) {
            float bj = b3[jm0 + a];
#pragma unroll
            for (int b = 0; b < 4; ++b)
                X[(jm0 + a) * 32 + r0 + b] = acc[a][b] + bj;
        }
        __syncthreads();
    }

    // ---- VQ: dist_k = ||e_k||^2 - 2*enc.e_k over 512 codes; top-2 + argmin ----
    {
        float bv1[4], bv2[4];
        int bk1[4];
        float acc[2][8][4];
#pragma unroll
        for (int p = 0; p < 2; ++p)
#pragma unroll
            for (int a = 0; a < 8; ++a)
#pragma unroll
                for (int b = 0; b < 4; ++b) acc[p][a][b] = 0.f;
        float4 qa = *(const float4*)(emb + (size_t)t * 128);
        float4 qb = *(const float4*)(emb + (size_t)(t + 256) * 128);
        for (int d0 = 0; d0 < 128; d0 += 4) {
            __syncthreads();
            WC[0 * 512 + t] = qa.x; WC[1 * 512 + t] = qa.y;
            WC[2 * 512 + t] = qa.z; WC[3 * 512 + t] = qa.w;
            WC[0 * 512 + 256 + t] = qb.x; WC[1 * 512 + 256 + t] = qb.y;
            WC[2 * 512 + 256 + t] = qb.z; WC[3 * 512 + 256 + t] = qb.w;
            __syncthreads();
            if (d0 + 4 < 128) {
                qa = *(const float4*)(emb + (size_t)t * 128 + d0 + 4);
                qb = *(const float4*)(emb + (size_t)(t + 256) * 128 + d0 + 4);
            }
#pragma unroll
            for (int i = 0; i < 4; ++i) {
                float4 h = *(const float4*)&X[(d0 + i) * 32 + r0];
                float hv[4] = {h.x, h.y, h.z, h.w};
#pragma unroll
                for (int p = 0; p < 2; ++p) {
                    float4 w0 = *(const float4*)&WC[i * 512 + p * 256 + j0];
                    float4 w1v = *(const float4*)&WC[i * 512 + p * 256 + j0 + 4];
                    float wv[8] = {w0.x, w0.y, w0.z, w0.w, w1v.x, w1v.y, w1v.z, w1v.w};
#pragma unroll
                    for (int a = 0; a < 8; ++a)
#pragma unroll
                        for (int b = 0; b < 4; ++b) acc[p][a][b] += wv[a] * hv[b];
                }
            }
        }
#pragma unroll
        for (int b = 0; b < 4; ++b) { bv1[b] = 1e30f; bv2[b] = 1e30f; bk1[b] = 0; }
#pragma unroll
        for (int p = 0; p < 2; ++p)
#pragma unroll
            for (int a = 0; a < 8; ++a) {
                int k = p * 256 + j0 + a;
                float ek = ws[WS_E2 + k];
#pragma unroll
                for (int b = 0; b < 4; ++b) {
                    float dd = ek - 2.f * acc[p][a][b];
                    if (dd < bv1[b]) { bv2[b] = bv1[b]; bv1[b] = dd; bk1[b] = k; }
                    else if (dd < bv2[b]) bv2[b] = dd;
                }
            }
        // butterfly top-2 merge across the 32 tx lanes (masks <32 stay in half-wave)
#pragma unroll
        for (int m = 1; m < 32; m <<= 1) {
#pragma unroll
            for (int b = 0; b < 4; ++b) {
                float ov1 = __shfl_xor(bv1[b], m);
                int ok1 = __shfl_xor(bk1[b], m);
                float ov2 = __shfl_xor(bv2[b], m);
                if (ov1 < bv1[b] || (ov1 == bv1[b] && ok1 < bk1[b])) {
                    bv2[b] = fminf(bv1[b], ov2);
                    bv1[b] = ov1; bk1[b] = ok1;
                } else {
                    bv2[b] = fminf(bv2[b], ov1);
                }
            }
        }
        if (tx == 0) {
#pragma unroll
            for (int b = 0; b < 4; ++b) {
                IDXR[r0 + b] = bk1[b];
                // NaN-safe: flag unless gap provably >= margin
                FLAGR[r0 + b] = (bv2[b] - bv1[b] >= MARGINF) ? 0 : 1;
            }
        }
    }
    __syncthreads();

    // ---- flag bit + idx output (row is structurally in [0,NB)) ----
    if (t < 32) {
        int row = row0 + t;
        if (FLAGR[t])
            atomicOr((unsigned int*)ws + WS_MASK + (row >> 5), 1u << (row & 31));
        out[row] = (float)IDXR[t];
    }

    // ---- gather q -> X[128..256), vq loss, write q_st (fp32) ----
    float lvq = 0.f, lrec = 0.f;
#pragma unroll
    for (int e = 0; e < 16; ++e) {
        int ii = e * 256 + t;
        int d = ii & 127, r = ii >> 7;
        int k = IDXR[r];
        float q = emb[(size_t)k * 128 + d];
        X[(128 + d) * 32 + r] = q;
        float en = X[d * 32 + r];
        if (!FLAGR[r]) lvq += (en - q) * (en - q);
        out[NB + (size_t)(row0 + r) * 128 + d] = q;
    }
    __syncthreads();

    // ---- decoder ----
    gemm_out256(d1w, d1b, 128, X + 128 * 32, Y, WC, t, j0, r0, true);
    gemm_out256(d2w, d2b, 256, Y, X, WC, t, j0, r0, true);

    if (t < 192) {
        int jj = t >> 5, r = t & 31;
        const float* wr = rw + jj * 256;
        float a0 = 0.f, a1 = 0.f, a2 = 0.f, a3 = 0.f;
        for (int i = 0; i < 256; i += 4) {
            a0 += wr[i] * X[i * 32 + r];
            a1 += wr[i + 1] * X[(i + 1) * 32 + r];
            a2 += wr[i + 2] * X[(i + 2) * 32 + r];
            a3 += wr[i + 3] * X[(i + 3) * 32 + r];
        }
        float rec = tanhf(rb[jj] + (a0 + a1) + (a2 + a3));
        float df = rec - AT[jj * 32 + r];
        if (!FLAGR[r]) lrec = df * df;
    }

    // ---- block loss reduction -> global double atomics ----
#pragma unroll
    for (int m = 1; m < 64; m <<= 1) {
        lvq += __shfl_xor(lvq, m);
        lrec += __shfl_xor(lrec, m);
    }
    if ((t & 63) == 0) { RED[t >> 6] = lvq; RED[4 + (t >> 6)] = lrec; }
    __syncthreads();
    if (t == 0) {
        atomicAdd((double*)ws + 0, (double)((RED[0] + RED[1]) + (RED[2] + RED[3])));
        atomicAdd((double*)ws + 1, (double)((RED[4] + RED[5]) + (RED[6] + RED[7])));
    }
}

// fp64 recompute of ambiguous rows; row derived from the bitmask word index,
// so it is ALWAYS in [0, NB).
__global__ __launch_bounds__(256) void vqvae_fix(
    const float* __restrict__ action,
    const float* __restrict__ w1, const float* __restrict__ b1,
    const float* __restrict__ w2, const float* __restrict__ b2,
    const float* __restrict__ w3, const float* __restrict__ b3,
    const float* __restrict__ emb,
    const float* __restrict__ d1w, const float* __restrict__ d1b,
    const float* __restrict__ d2w, const float* __restrict__ d2b,
    const float* __restrict__ rw, const float* __restrict__ rb,
    float* __restrict__ out, float* __restrict__ ws)
{
    __shared__ double H1[256];
    __shared__ double H2[256];
    __shared__ double ENC[128];
    __shared__ double QD[128];
    __shared__ double SRED[256];
    __shared__ int SK[256];
    __shared__ double SA[6];

    const int t = threadIdx.x;
    const unsigned int word = ((const unsigned int*)ws)[WS_MASK + blockIdx.x];
    if (word == 0u) return;  // uniform across block

    for (int bit = 0; bit < 32; ++bit) {
        if (!(word & (1u << bit))) continue;  // uniform
        const int row = (blockIdx.x << 5) + bit;

        if (t < 6) SA[t] = (double)action[(size_t)row * 6 + t];
        __syncthreads();
        {
            double a = (double)b1[t];
#pragma unroll
            for (int i = 0; i < 6; ++i) a += (double)w1[t * 6 + i] * SA[i];
            H1[t] = a > 0.0 ? a : 0.0;
        }
        __syncthreads();
        {
            const float* w = w2 + (size_t)t * 256;
            double a0 = 0, a1 = 0, a2 = 0, a3 = 0;
            for (int i = 0; i < 256; i += 4) {
                a0 += (double)w[i] * H1[i];     a1 += (double)w[i + 1] * H1[i + 1];
                a2 += (double)w[i + 2] * H1[i + 2]; a3 += (double)w[i + 3] * H1[i + 3];
            }
            double a = (double)b2[t] + a0 + a1 + a2 + a3;
            H2[t] = a > 0.0 ? a : 0.0;
        }
        __syncthreads();
        if (t < 128) {
            const float* w = w3 + (size_t)t * 256;
            double a0 = 0, a1 = 0, a2 = 0, a3 = 0;
            for (int i = 0; i < 256; i += 4) {
                a0 += (double)w[i] * H2[i];     a1 += (double)w[i + 1] * H2[i + 1];
                a2 += (double)w[i + 2] * H2[i + 2]; a3 += (double)w[i + 3] * H2[i + 3];
            }
            ENC[t] = (double)b3[t] + a0 + a1 + a2 + a3;
        }
        __syncthreads();
        double best = 1e300; int bk = 0;
#pragma unroll
        for (int kk = 0; kk < 2; ++kk) {
            int k = t + kk * 256;
            const float* e = emb + (size_t)k * 128;
            double s0 = 0, s1 = 0;
            for (int d = 0; d < 128; d += 2) {
                double df0 = ENC[d] - (double)e[d];
                double df1 = ENC[d + 1] - (double)e[d + 1];
                s0 += df0 * df0; s1 += df1 * df1;
            }
            double s = s0 + s1;
            if (s < best) { best = s; bk = k; }
        }
        SRED[t] = best; SK[t] = bk;
        __syncthreads();
        for (int st = 128; st > 0; st >>= 1) {
            if (t < st) {
                double ov = SRED[t + st]; int ok = SK[t + st];
                if (ov < SRED[t] || (ov == SRED[t] && ok < SK[t])) { SRED[t] = ov; SK[t] = ok; }
            }
            __syncthreads();
        }
        const int bestk = SK[0];
        double lv = 0.0;
        if (t < 128) {
            double q = (double)emb[(size_t)bestk * 128 + t];
            QD[t] = q;
            double df = ENC[t] - q;
            lv = df * df;
            out[NB + (size_t)row * 128 + t] = (float)q;
        }
        if (t == 0) out[row] = (float)bestk;
        __syncthreads();
        {
            const float* w = d1w + (size_t)t * 128;
            double a0 = 0, a1 = 0;
            for (int i = 0; i < 128; i += 2) {
                a0 += (double)w[i] * QD[i]; a1 += (double)w[i + 1] * QD[i + 1];
            }
            double a = (double)d1b[t] + a0 + a1;
            H1[t] = a > 0.0 ? a : 0.0;
        }
        __syncthreads();
        {
            const float* w = d2w + (size_t)t * 256;
            double a0 = 0, a1 = 0, a2 = 0, a3 = 0;
            for (int i = 0; i < 256; i += 4) {
                a0 += (double)w[i] * H1[i];     a1 += (double)w[i + 1] * H1[i + 1];
                a2 += (double)w[i + 2] * H1[i + 2]; a3 += (double)w[i + 3] * H1[i + 3];
            }
            double a = (double)d2b[t] + a0 + a1 + a2 + a3;
            H2[t] = a > 0.0 ? a : 0.0;
        }
        __syncthreads();
        double lr = 0.0;
        if (t < 6) {
            const float* w = rw + (size_t)t * 256;
            double a0 = 0, a1 = 0;
            for (int i = 0; i < 256; i += 2) {
                a0 += (double)w[i] * H2[i]; a1 += (double)w[i + 1] * H2[i + 1];
            }
            double rec = tanh((double)rb[t] + a0 + a1);
            double df = rec - SA[t];
            lr = df * df;
        }
        SRED[t] = lv;
        __syncthreads();
        for (int st = 128; st > 0; st >>= 1) {
            if (t < st) SRED[t] += SRED[t + st];
            __syncthreads();
        }
        if (t == 0) atomicAdd((double*)ws + 0, SRED[0]);
        if (t < 6) atomicAdd((double*)ws + 1, lr);
        __syncthreads();
    }
}

__global__ void vqvae_fin(const float* __restrict__ ws, float* __restrict__ out) {
    if (threadIdx.x == 0 && blockIdx.x == 0) {
        const double* D = (const double*)ws;
        double loss = D[1] / ((double)NB * 6.0) + 1.25 * (D[0] / ((double)NB * 128.0));
        out[(size_t)NB * 129] = (float)loss;
    }
}

extern "C" void kernel_launch(void* const* d_in, const int* in_sizes, int n_in,
                              void* d_out, int out_size, void* d_ws, size_t ws_size,
                              hipStream_t stream) {
    const float* action = (const float*)d_in[0];
    const float* w1 = (const float*)d_in[1];
    const float* b1 = (const float*)d_in[2];
    const float* w2 = (const float*)d_in[3];
    const float* b2 = (const float*)d_in[4];
    const float* w3 = (const float*)d_in[5];
    const float* b3 = (const float*)d_in[6];
    const float* emb = (const float*)d_in[7];
    const float* d1w = (const float*)d_in[8];
    const float* d1b = (const float*)d_in[9];
    const float* d2w = (const float*)d_in[10];
    const float* d2b = (const float*)d_in[11];
    const float* rw = (const float*)d_in[12];
    const float* rb = (const float*)d_in[13];
    float* out = (float*)d_out;
    float* ws = (float*)d_ws;

    size_t clear = ws_size < (size_t)WS_NEED ? ws_size : (size_t)WS_NEED;
    hipMemsetAsync(d_ws, 0, clear, stream);

    prep_kernel<<<2, 256, 0, stream>>>(emb, ws);
    vqvae_main<<<NB / 32, 256, 0, stream>>>(action, w1, b1, w2, b2, w3, b3, emb,
                                            d1w, d1b, d2w, d2b, rw, rb, out, ws);
    vqvae_fix<<<NB / 32, 256, 0, stream>>>(action, w1, b1, w2, b2, w3, b3, emb,
                                           d1w, d1b, d2w, d2b, rw, rb, out, ws);
    vqvae_fin<<<1, 64, 0, stream>>>(ws, out);
}

// Round 4
// 1253.663 us; speedup vs baseline: 1.1416x; 1.1416x over previous
//
#include <hip/hip_runtime.h>
#include <hip/hip_bf16.h>

#define NB 131072
#define MARGINF 1e-6f
#define WS_E2 16          // float index of e2[512]
#define WS_MASK 528       // float index of flag bitmask (4096 u32 words)
#define WS_MASKW 4096     // NB/32
#define WS_NEED ((WS_MASK + WS_MASKW) * 4)

// XOR swizzle for [row][32] f32 tiles: keeps float4-along-r contiguous,
// spreads same-column accesses across the 8 bank-quads.
#define SWC(j) ((((j) >> 2) & 7) << 2)

__global__ void prep_kernel(const float* __restrict__ emb, float* __restrict__ ws) {
    int t = blockIdx.x * 256 + threadIdx.x;
    if (t < 512) {
        const float* e = emb + (size_t)t * 128;
        float s0 = 0.f, s1 = 0.f, s2 = 0.f, s3 = 0.f;
        for (int d = 0; d < 128; d += 4) {
            s0 += e[d] * e[d];
            s1 += e[d + 1] * e[d + 1];
            s2 += e[d + 2] * e[d + 2];
            s3 += e[d + 3] * e[d + 3];
        }
        ws[WS_E2 + t] = (s0 + s1) + (s2 + s3);
    }
}

// Register-tiled GEMM: 256 outputs x 32 rows, per-thread j in {4tx, 128+4tx}+0..3.
// W is [256][IN] row-major (global), hin/hout are swizzled LDS [*][32] tiles.
static __device__ __forceinline__ void gemm_out256(
    const float* __restrict__ W, const float* __restrict__ bias, int IN,
    const float* __restrict__ hin, float* __restrict__ hout,
    float* __restrict__ WC, int t, int tx, int r0, bool do_relu)
{
    float acc[2][4][4];
#pragma unroll
    for (int g = 0; g < 2; ++g)
#pragma unroll
        for (int a = 0; a < 4; ++a)
#pragma unroll
            for (int b = 0; b < 4; ++b) acc[g][a][b] = 0.f;

    float4 pa = *(const float4*)(W + (size_t)t * IN);
    float4 pb = *(const float4*)(W + (size_t)t * IN + 4);

    for (int i0 = 0; i0 < IN; i0 += 8) {
        __syncthreads();
        WC[0 * 256 + t] = pa.x; WC[1 * 256 + t] = pa.y;
        WC[2 * 256 + t] = pa.z; WC[3 * 256 + t] = pa.w;
        WC[4 * 256 + t] = pb.x; WC[5 * 256 + t] = pb.y;
        WC[6 * 256 + t] = pb.z; WC[7 * 256 + t] = pb.w;
        __syncthreads();
        if (i0 + 8 < IN) {
            pa = *(const float4*)(W + (size_t)t * IN + i0 + 8);
            pb = *(const float4*)(W + (size_t)t * IN + i0 + 12);
        }
#pragma unroll
        for (int i = 0; i < 8; ++i) {
            int row = i0 + i;
            float4 h = *(const float4*)&hin[row * 32 + (r0 ^ SWC(row))];
            float4 w0 = *(const float4*)&WC[i * 256 + 4 * tx];
            float4 w1v = *(const float4*)&WC[i * 256 + 128 + 4 * tx];
            float wv0[4] = {w0.x, w0.y, w0.z, w0.w};
            float wv1[4] = {w1v.x, w1v.y, w1v.z, w1v.w};
            float hv[4] = {h.x, h.y, h.z, h.w};
#pragma unroll
            for (int a = 0; a < 4; ++a)
#pragma unroll
                for (int b = 0; b < 4; ++b) {
                    acc[0][a][b] += wv0[a] * hv[b];
                    acc[1][a][b] += wv1[a] * hv[b];
                }
        }
    }
#pragma unroll
    for (int g = 0; g < 2; ++g)
#pragma unroll
        for (int a = 0; a < 4; ++a) {
            int j = g * 128 + 4 * tx + a;
            float bj = bias[j];
            float4 v;
            v.x = acc[g][a][0] + bj; v.y = acc[g][a][1] + bj;
            v.z = acc[g][a][2] + bj; v.w = acc[g][a][3] + bj;
            if (do_relu) {
                v.x = fmaxf(v.x, 0.f); v.y = fmaxf(v.y, 0.f);
                v.z = fmaxf(v.z, 0.f); v.w = fmaxf(v.w, 0.f);
            }
            *(float4*)&hout[j * 32 + (r0 ^ SWC(j))] = v;
        }
    __syncthreads();
}

__global__ __launch_bounds__(256, 2) void vqvae_main(
    const float* __restrict__ action,
    const float* __restrict__ w1, const float* __restrict__ b1,
    const float* __restrict__ w2, const float* __restrict__ b2,
    const float* __restrict__ w3, const float* __restrict__ b3,
    const float* __restrict__ emb,
    const float* __restrict__ d1w, const float* __restrict__ d1b,
    const float* __restrict__ d2w, const float* __restrict__ d2b,
    const float* __restrict__ rw, const float* __restrict__ rb,
    float* __restrict__ out, float* __restrict__ ws)
{
    __shared__ float X[256 * 32];
    __shared__ float Y[256 * 32];
    __shared__ float WC[2048];
    __shared__ float AT[6 * 32];
    __shared__ int IDXR[32];
    __shared__ int FLAGR[32];
    __shared__ float RED[8];

    const int t = threadIdx.x;
    const int tx = t & 31, ty = t >> 5;
    const int r0 = ty * 4;
    const int row0 = blockIdx.x * 32;

    // ---- load action tile (coalesced), store transposed [i][r] (unswizzled) ----
    if (t < 192) {
        int r = t / 6, i = t - r * 6;
        AT[i * 32 + r] = action[(size_t)row0 * 6 + t];
    }
    __syncthreads();

    // ---- enc1: 6 -> 256, relu, -> X ----
    {
#pragma unroll
        for (int i = 0; i < 6; ++i) WC[i * 256 + t] = w1[t * 6 + i];
        __syncthreads();
        float acc[2][4][4];
#pragma unroll
        for (int g = 0; g < 2; ++g)
#pragma unroll
            for (int a = 0; a < 4; ++a)
#pragma unroll
                for (int b = 0; b < 4; ++b) acc[g][a][b] = 0.f;
#pragma unroll
        for (int i = 0; i < 6; ++i) {
            float4 h = *(const float4*)&AT[i * 32 + r0];
            float4 w0 = *(const float4*)&WC[i * 256 + 4 * tx];
            float4 w1v = *(const float4*)&WC[i * 256 + 128 + 4 * tx];
            float wv0[4] = {w0.x, w0.y, w0.z, w0.w};
            float wv1[4] = {w1v.x, w1v.y, w1v.z, w1v.w};
            float hv[4] = {h.x, h.y, h.z, h.w};
#pragma unroll
            for (int a = 0; a < 4; ++a)
#pragma unroll
                for (int b = 0; b < 4; ++b) {
                    acc[0][a][b] += wv0[a] * hv[b];
                    acc[1][a][b] += wv1[a] * hv[b];
                }
        }
#pragma unroll
        for (int g = 0; g < 2; ++g)
#pragma unroll
            for (int a = 0; a < 4; ++a) {
                int j = g * 128 + 4 * tx + a;
                float bj = b1[j];
                float4 v;
                v.x = fmaxf(acc[g][a][0] + bj, 0.f);
                v.y = fmaxf(acc[g][a][1] + bj, 0.f);
                v.z = fmaxf(acc[g][a][2] + bj, 0.f);
                v.w = fmaxf(acc[g][a][3] + bj, 0.f);
                *(float4*)&X[j * 32 + (r0 ^ SWC(j))] = v;
            }
        __syncthreads();
    }

    // ---- enc2: 256 -> 256, relu, X -> Y ----
    gemm_out256(w2, b2, 256, X, Y, WC, t, tx, r0, true);

    // ---- mu: 256 -> 128 (no relu), Y -> X[0..128) ----
    {
        float acc[4][4];
#pragma unroll
        for (int a = 0; a < 4; ++a)
#pragma unroll
            for (int b = 0; b < 4; ++b) acc[a][b] = 0.f;
        float4 pa, pb;
        if (t < 128) {
            pa = *(const float4*)(w3 + (size_t)t * 256);
            pb = *(const float4*)(w3 + (size_t)t * 256 + 4);
        }
        for (int i0 = 0; i0 < 256; i0 += 8) {
            __syncthreads();
            if (t < 128) {
                WC[0 * 128 + t] = pa.x; WC[1 * 128 + t] = pa.y;
                WC[2 * 128 + t] = pa.z; WC[3 * 128 + t] = pa.w;
                WC[4 * 128 + t] = pb.x; WC[5 * 128 + t] = pb.y;
                WC[6 * 128 + t] = pb.z; WC[7 * 128 + t] = pb.w;
            }
            __syncthreads();
            if (t < 128 && i0 + 8 < 256) {
                pa = *(const float4*)(w3 + (size_t)t * 256 + i0 + 8);
                pb = *(const float4*)(w3 + (size_t)t * 256 + i0 + 12);
            }
#pragma unroll
            for (int i = 0; i < 8; ++i) {
                int row = i0 + i;
                float4 h = *(const float4*)&Y[row * 32 + (r0 ^ SWC(row))];
                float4 w0 = *(const float4*)&WC[i * 128 + 4 * tx];
                float wv[4] = {w0.x, w0.y, w0.z, w0.w};
                float hv[4] = {h.x, h.y, h.z, h.w};
#pragma unroll
                for (int a = 0; a < 4; ++a)
#pragma unroll
                    for (int b = 0; b < 4; ++b) acc[a][b] += wv[a] * hv[b];
            }
        }
#pragma unroll
        for (int a = 0; a < 4; ++a) {
            int j = 4 * tx + a;
            float bj = b3[j];
            float4 v;
            v.x = acc[a][0] + bj; v.y = acc[a][1] + bj;
            v.z = acc[a][2] + bj; v.w = acc[a][3] + bj;
            *(float4*)&X[j * 32 + (r0 ^ SWC(j))] = v;
        }
        __syncthreads();
    }

    // ---- VQ: dist_k = ||e_k||^2 - 2*enc.e_k over 512 codes; top-2 + argmin ----
    {
        float bv1[4], bv2[4];
        int bk1[4];
        float acc[4][4][4];
#pragma unroll
        for (int p = 0; p < 4; ++p)
#pragma unroll
            for (int a = 0; a < 4; ++a)
#pragma unroll
                for (int b = 0; b < 4; ++b) acc[p][a][b] = 0.f;
        float4 qa = *(const float4*)(emb + (size_t)t * 128);
        float4 qb = *(const float4*)(emb + (size_t)(t + 256) * 128);
        for (int d0 = 0; d0 < 128; d0 += 4) {
            __syncthreads();
            WC[0 * 512 + t] = qa.x; WC[1 * 512 + t] = qa.y;
            WC[2 * 512 + t] = qa.z; WC[3 * 512 + t] = qa.w;
            WC[0 * 512 + 256 + t] = qb.x; WC[1 * 512 + 256 + t] = qb.y;
            WC[2 * 512 + 256 + t] = qb.z; WC[3 * 512 + 256 + t] = qb.w;
            __syncthreads();
            if (d0 + 4 < 128) {
                qa = *(const float4*)(emb + (size_t)t * 128 + d0 + 4);
                qb = *(const float4*)(emb + (size_t)(t + 256) * 128 + d0 + 4);
            }
#pragma unroll
            for (int i = 0; i < 4; ++i) {
                int row = d0 + i;
                float4 h = *(const float4*)&X[row * 32 + (r0 ^ SWC(row))];
                float hv[4] = {h.x, h.y, h.z, h.w};
#pragma unroll
                for (int p = 0; p < 4; ++p) {
                    float4 w0 = *(const float4*)&WC[i * 512 + p * 128 + 4 * tx];
                    float wv[4] = {w0.x, w0.y, w0.z, w0.w};
#pragma unroll
                    for (int a = 0; a < 4; ++a)
#pragma unroll
                        for (int b = 0; b < 4; ++b) acc[p][a][b] += wv[a] * hv[b];
                }
            }
        }
#pragma unroll
        for (int b = 0; b < 4; ++b) { bv1[b] = 1e30f; bv2[b] = 1e30f; bk1[b] = 0; }
        // scan in ascending k within the thread (p major, a minor)
#pragma unroll
        for (int p = 0; p < 4; ++p)
#pragma unroll
            for (int a = 0; a < 4; ++a) {
                int k = p * 128 + 4 * tx + a;
                float ek = ws[WS_E2 + k];
#pragma unroll
                for (int b = 0; b < 4; ++b) {
                    float dd = ek - 2.f * acc[p][a][b];
                    if (dd < bv1[b]) { bv2[b] = bv1[b]; bv1[b] = dd; bk1[b] = k; }
                    else if (dd < bv2[b]) bv2[b] = dd;
                }
            }
        // butterfly top-2 merge across the 32 tx lanes (masks <32 stay in half-wave)
#pragma unroll
        for (int m = 1; m < 32; m <<= 1) {
#pragma unroll
            for (int b = 0; b < 4; ++b) {
                float ov1 = __shfl_xor(bv1[b], m);
                int ok1 = __shfl_xor(bk1[b], m);
                float ov2 = __shfl_xor(bv2[b], m);
                if (ov1 < bv1[b] || (ov1 == bv1[b] && ok1 < bk1[b])) {
                    bv2[b] = fminf(bv1[b], ov2);
                    bv1[b] = ov1; bk1[b] = ok1;
                } else {
                    bv2[b] = fminf(bv2[b], ov1);
                }
            }
        }
        if (tx == 0) {
#pragma unroll
            for (int b = 0; b < 4; ++b) {
                IDXR[r0 + b] = bk1[b];
                // NaN-safe: flag unless gap provably >= margin
                FLAGR[r0 + b] = (bv2[b] - bv1[b] >= MARGINF) ? 0 : 1;
            }
        }
    }
    __syncthreads();

    // ---- flag bit + idx output (row is structurally in [0,NB)) ----
    if (t < 32) {
        int row = row0 + t;
        if (FLAGR[t])
            atomicOr((unsigned int*)ws + WS_MASK + (row >> 5), 1u << (row & 31));
        out[row] = (float)IDXR[t];
    }

    // ---- gather q -> X[128..256), vq loss, write q_st (fp32, float4 LDS) ----
    float lvq = 0.f, lrec = 0.f;
    {
        int d = t & 127, rq = t >> 7;
        int cd = SWC(d);  // SWC(128+d) == SWC(d)
#pragma unroll
        for (int e = 0; e < 4; ++e) {
            int rr = (rq + 2 * e) * 4;
            float4 en = *(const float4*)&X[d * 32 + (rr ^ cd)];
            float q0 = emb[(size_t)IDXR[rr + 0] * 128 + d];
            float q1 = emb[(size_t)IDXR[rr + 1] * 128 + d];
            float q2 = emb[(size_t)IDXR[rr + 2] * 128 + d];
            float q3 = emb[(size_t)IDXR[rr + 3] * 128 + d];
            float4 qv; qv.x = q0; qv.y = q1; qv.z = q2; qv.w = q3;
            *(float4*)&X[(128 + d) * 32 + (rr ^ cd)] = qv;
            if (!FLAGR[rr + 0]) lvq += (en.x - q0) * (en.x - q0);
            if (!FLAGR[rr + 1]) lvq += (en.y - q1) * (en.y - q1);
            if (!FLAGR[rr + 2]) lvq += (en.z - q2) * (en.z - q2);
            if (!FLAGR[rr + 3]) lvq += (en.w - q3) * (en.w - q3);
            out[NB + (size_t)(row0 + rr + 0) * 128 + d] = q0;
            out[NB + (size_t)(row0 + rr + 1) * 128 + d] = q1;
            out[NB + (size_t)(row0 + rr + 2) * 128 + d] = q2;
            out[NB + (size_t)(row0 + rr + 3) * 128 + d] = q3;
        }
    }
    __syncthreads();

    // ---- decoder ----
    gemm_out256(d1w, d1b, 128, X + 128 * 32, Y, WC, t, tx, r0, true);
    gemm_out256(d2w, d2b, 256, Y, X, WC, t, tx, r0, true);

    if (t < 192) {
        int jj = t >> 5, r = t & 31;
        const float* wr = rw + jj * 256;
        float a0 = 0.f, a1 = 0.f, a2 = 0.f, a3 = 0.f;
        for (int i = 0; i < 256; i += 4) {
            a0 += wr[i] * X[i * 32 + (r ^ SWC(i))];
            a1 += wr[i + 1] * X[(i + 1) * 32 + (r ^ SWC(i + 1))];
            a2 += wr[i + 2] * X[(i + 2) * 32 + (r ^ SWC(i + 2))];
            a3 += wr[i + 3] * X[(i + 3) * 32 + (r ^ SWC(i + 3))];
        }
        float rec = tanhf(rb[jj] + (a0 + a1) + (a2 + a3));
        float df = rec - AT[jj * 32 + r];
        if (!FLAGR[r]) lrec = df * df;
    }

    // ---- block loss reduction -> global double atomics ----
#pragma unroll
    for (int m = 1; m < 64; m <<= 1) {
        lvq += __shfl_xor(lvq, m);
        lrec += __shfl_xor(lrec, m);
    }
    if ((t & 63) == 0) { RED[t >> 6] = lvq; RED[4 + (t >> 6)] = lrec; }
    __syncthreads();
    if (t == 0) {
        atomicAdd((double*)ws + 0, (double)((RED[0] + RED[1]) + (RED[2] + RED[3])));
        atomicAdd((double*)ws + 1, (double)((RED[4] + RED[5]) + (RED[6] + RED[7])));
    }
}

// fp64 recompute of ambiguous rows; row derived from the bitmask word index,
// so it is ALWAYS in [0, NB).
__global__ __launch_bounds__(256) void vqvae_fix(
    const float* __restrict__ action,
    const float* __restrict__ w1, const float* __restrict__ b1,
    const float* __restrict__ w2, const float* __restrict__ b2,
    const float* __restrict__ w3, const float* __restrict__ b3,
    const float* __restrict__ emb,
    const float* __restrict__ d1w, const float* __restrict__ d1b,
    const float* __restrict__ d2w, const float* __restrict__ d2b,
    const float* __restrict__ rw, const float* __restrict__ rb,
    float* __restrict__ out, float* __restrict__ ws)
{
    __shared__ double H1[256];
    __shared__ double H2[256];
    __shared__ double ENC[128];
    __shared__ double QD[128];
    __shared__ double SRED[256];
    __shared__ int SK[256];
    __shared__ double SA[6];

    const int t = threadIdx.x;
    const unsigned int word = ((const unsigned int*)ws)[WS_MASK + blockIdx.x];
    if (word == 0u) return;  // uniform across block

    for (int bit = 0; bit < 32; ++bit) {
        if (!(word & (1u << bit))) continue;  // uniform
        const int row = (blockIdx.x << 5) + bit;

        if (t < 6) SA[t] = (double)action[(size_t)row * 6 + t];
        __syncthreads();
        {
            double a = (double)b1[t];
#pragma unroll
            for (int i = 0; i < 6; ++i) a += (double)w1[t * 6 + i] * SA[i];
            H1[t] = a > 0.0 ? a : 0.0;
        }
        __syncthreads();
        {
            const float* w = w2 + (size_t)t * 256;
            double a0 = 0, a1 = 0, a2 = 0, a3 = 0;
            for (int i = 0; i < 256; i += 4) {
                a0 += (double)w[i] * H1[i];     a1 += (double)w[i + 1] * H1[i + 1];
                a2 += (double)w[i + 2] * H1[i + 2]; a3 += (double)w[i + 3] * H1[i + 3];
            }
            double a = (double)b2[t] + a0 + a1 + a2 + a3;
            H2[t] = a > 0.0 ? a : 0.0;
        }
        __syncthreads();
        if (t < 128) {
            const float* w = w3 + (size_t)t * 256;
            double a0 = 0, a1 = 0, a2 = 0, a3 = 0;
            for (int i = 0; i < 256; i += 4) {
                a0 += (double)w[i] * H2[i];     a1 += (double)w[i + 1] * H2[i + 1];
                a2 += (double)w[i + 2] * H2[i + 2]; a3 += (double)w[i + 3] * H2[i + 3];
            }
            ENC[t] = (double)b3[t] + a0 + a1 + a2 + a3;
        }
        __syncthreads();
        double best = 1e300; int bk = 0;
#pragma unroll
        for (int kk = 0; kk < 2; ++kk) {
            int k = t + kk * 256;
            const float* e = emb + (size_t)k * 128;
            double s0 = 0, s1 = 0;
            for (int d = 0; d < 128; d += 2) {
                double df0 = ENC[d] - (double)e[d];
                double df1 = ENC[d + 1] - (double)e[d + 1];
                s0 += df0 * df0; s1 += df1 * df1;
            }
            double s = s0 + s1;
            if (s < best) { best = s; bk = k; }
        }
        SRED[t] = best; SK[t] = bk;
        __syncthreads();
        for (int st = 128; st > 0; st >>= 1) {
            if (t < st) {
                double ov = SRED[t + st]; int ok = SK[t + st];
                if (ov < SRED[t] || (ov == SRED[t] && ok < SK[t])) { SRED[t] = ov; SK[t] = ok; }
            }
            __syncthreads();
        }
        const int bestk = SK[0];
        double lv = 0.0;
        if (t < 128) {
            double q = (double)emb[(size_t)bestk * 128 + t];
            QD[t] = q;
            double df = ENC[t] - q;
            lv = df * df;
            out[NB + (size_t)row * 128 + t] = (float)q;
        }
        if (t == 0) out[row] = (float)bestk;
        __syncthreads();
        {
            const float* w = d1w + (size_t)t * 128;
            double a0 = 0, a1 = 0;
            for (int i = 0; i < 128; i += 2) {
                a0 += (double)w[i] * QD[i]; a1 += (double)w[i + 1] * QD[i + 1];
            }
            double a = (double)d1b[t] + a0 + a1;
            H1[t] = a > 0.0 ? a : 0.0;
        }
        __syncthreads();
        {
            const float* w = d2w + (size_t)t * 256;
            double a0 = 0, a1 = 0, a2 = 0, a3 = 0;
            for (int i = 0; i < 256; i += 4) {
                a0 += (double)w[i] * H1[i];     a1 += (double)w[i + 1] * H1[i + 1];
                a2 += (double)w[i + 2] * H1[i + 2]; a3 += (double)w[i + 3] * H1[i + 3];
            }
            double a = (double)d2b[t] + a0 + a1 + a2 + a3;
            H2[t] = a > 0.0 ? a : 0.0;
        }
        __syncthreads();
        double lr = 0.0;
        if (t < 6) {
            const float* w = rw + (size_t)t * 256;
            double a0 = 0, a1 = 0;
            for (int i = 0; i < 256; i += 2) {
                a0 += (double)w[i] * H2[i]; a1 += (double)w[i + 1] * H2[i + 1];
            }
            double rec = tanh((double)rb[t] + a0 + a1);
            double df = rec - SA[t];
            lr = df * df;
        }
        SRED[t] = lv;
        __syncthreads();
        for (int st = 128; st > 0; st >>= 1) {
            if (t < st) SRED[t] += SRED[t + st];
            __syncthreads();
        }
        if (t == 0) atomicAdd((double*)ws + 0, SRED[0]);
        if (t < 6) atomicAdd((double*)ws + 1, lr);
        __syncthreads();
    }
}

__global__ void vqvae_fin(const float* __restrict__ ws, float* __restrict__ out) {
    if (threadIdx.x == 0 && blockIdx.x == 0) {
        const double* D = (const double*)ws;
        double loss = D[1] / ((double)NB * 6.0) + 1.25 * (D[0] / ((double)NB * 128.0));
        out[(size_t)NB * 129] = (float)loss;
    }
}

extern "C" void kernel_launch(void* const* d_in, const int* in_sizes, int n_in,
                              void* d_out, int out_size, void* d_ws, size_t ws_size,
                              hipStream_t stream) {
    const float* action = (const float*)d_in[0];
    const float* w1 = (const float*)d_in[1];
    const float* b1 = (const float*)d_in[2];
    const float* w2 = (const float*)d_in[3];
    const float* b2 = (const float*)d_in[4];
    const float* w3 = (const float*)d_in[5];
    const float* b3 = (const float*)d_in[6];
    const float* emb = (const float*)d_in[7];
    const float* d1w = (const float*)d_in[8];
    const float* d1b = (const float*)d_in[9];
    const float* d2w = (const float*)d_in[10];
    const float* d2b = (const float*)d_in[11];
    const float* rw = (const float*)d_in[12];
    const float* rb = (const float*)d_in[13];
    float* out = (float*)d_out;
    float* ws = (float*)d_ws;

    size_t clear = ws_size < (size_t)WS_NEED ? ws_size : (size_t)WS_NEED;
    hipMemsetAsync(d_ws, 0, clear, stream);

    prep_kernel<<<2, 256, 0, stream>>>(emb, ws);
    vqvae_main<<<NB / 32, 256, 0, stream>>>(action, w1, b1, w2, b2, w3, b3, emb,
                                            d1w, d1b, d2w, d2b, rw, rb, out, ws);
    vqvae_fix<<<NB / 32, 256, 0, stream>>>(action, w1, b1, w2, b2, w3, b3, emb,
                                           d1w, d1b, d2w, d2b, rw, rb, out, ws);
    vqvae_fin<<<1, 64, 0, stream>>>(ws, out);
}

// Round 5
// 665.264 us; speedup vs baseline: 2.1512x; 1.8845x over previous
//
#include <hip/hip_runtime.h>
#include <hip/hip_bf16.h>

#define NB 131072
#define MARGINF 2e-6f
#define WS_E2 16          // float index of e2[512]
#define WS_MASK 528       // float index of flag bitmask (4096 u32 words)
#define WS_MASKW 4096     // NB/32
#define WS_BASE_BYTES 18496
#define WS_SPLIT_F 4624   // float index where bf16 split-weight region starts
// split region offsets (bf16 element units, relative to split base)
#define OFF_W2 0
#define OFF_W3 131072
#define OFF_EMB 196608
#define OFF_D1 327680
#define OFF_D2 393216
#define OFF_RW 524288
#define SPLIT_TOTAL 532480

typedef __attribute__((ext_vector_type(8))) short short8v;
typedef __attribute__((ext_vector_type(4))) float f32x4;
typedef __attribute__((ext_vector_type(4))) unsigned short ushort4v;

// XOR swizzle used by the fp32 fallback path
#define SWC(j) ((((j) >> 2) & 7) << 2)

__device__ __forceinline__ unsigned short bf16rn(float x) {
    unsigned u = __float_as_uint(x);
    unsigned r = u + 0x7fffu + ((u >> 16) & 1u);
    return (unsigned short)(r >> 16);
}
__device__ __forceinline__ void split2(float x, unsigned short& h, unsigned short& l) {
    h = bf16rn(x);
    float hf = __uint_as_float((unsigned)h << 16);
    l = bf16rn(x - hf);
}

// ---------------- prep: e2 + fragment-linear bf16 weight splits ----------------
// Fragment layout for mfma_f32_16x16x32_bf16 operand (16 rows x K):
// frag (tile jt, kchunk c, split s): 64 lanes x 8 bf16:
//   lane = ((k>>3)&3)<<4 | (o&15), elem e = k&7, k = c*32 + (lane>>4)*8 + e
// bf16 addr = base + ((jt*KC + c)*2 + s)*512 + lane*8 + e
__global__ void prep_kernel(
    const float* __restrict__ w2, const float* __restrict__ w3,
    const float* __restrict__ emb, const float* __restrict__ d1w,
    const float* __restrict__ d2w, const float* __restrict__ rw,
    float* __restrict__ ws, int do_splits)
{
    const int total = 512 + 266240;
    unsigned short* wsb = (unsigned short*)(ws + WS_SPLIT_F);
    for (int idx = blockIdx.x * 256 + threadIdx.x; idx < total; idx += gridDim.x * 256) {
        if (idx < 512) {
            const float* e = emb + (size_t)idx * 128;
            float s0 = 0.f, s1 = 0.f, s2 = 0.f, s3 = 0.f;
            for (int d = 0; d < 128; d += 4) {
                s0 += e[d] * e[d];     s1 += e[d + 1] * e[d + 1];
                s2 += e[d + 2] * e[d + 2]; s3 += e[d + 3] * e[d + 3];
            }
            ws[WS_E2 + idx] = (s0 + s1) + (s2 + s3);
            continue;
        }
        if (!do_splits) continue;
        int j = idx - 512;
        int base, K, o, k;
        float src;
        if (j < 65536) {            // w2: 256x256
            o = j >> 8; k = j & 255; base = OFF_W2; K = 256; src = w2[o * 256 + k];
        } else if (j < 98304) {     // w3: 128x256
            j -= 65536; o = j >> 8; k = j & 255; base = OFF_W3; K = 256; src = w3[o * 256 + k];
        } else if (j < 163840) {    // emb: 512x128 (B-operand: o = code, k = d)
            j -= 98304; o = j >> 7; k = j & 127; base = OFF_EMB; K = 128; src = emb[o * 128 + k];
        } else if (j < 196608) {    // d1w: 256x128
            j -= 163840; o = j >> 7; k = j & 127; base = OFF_D1; K = 128; src = d1w[o * 128 + k];
        } else if (j < 262144) {    // d2w: 256x256
            j -= 196608; o = j >> 8; k = j & 255; base = OFF_D2; K = 256; src = d2w[o * 256 + k];
        } else {                    // rw padded to 16 rows: 16x256
            j -= 262144; o = j >> 8; k = j & 255; base = OFF_RW; K = 256;
            src = (o < 6) ? rw[o * 256 + k] : 0.f;
        }
        unsigned short h, l;
        split2(src, h, l);
        int jt = o >> 4, c = k >> 5;
        int lane = (((k >> 3) & 3) << 4) | (o & 15);
        int e = k & 7;
        int a = base + ((jt * (K >> 5) + c) * 2) * 512 + lane * 8 + e;
        wsb[a] = h;
        wsb[a + 512] = l;
    }
}

// ---------------- MFMA main kernel ----------------
// 32 rows/block, 256 threads = 4 waves. Activations in LDS as hi/lo bf16
// [32 rows][264 K-pad]. All GEMMs: A = weight frags (global ws), B = activation
// frags (LDS), except VQ where A = enc frags (LDS), B = emb frags (global ws).

template<int NJT, int KC, bool RELU, bool SQSUM>
__device__ __forceinline__ void mfma_mlp(
    const short8v* __restrict__ Wf, const float* __restrict__ bias,
    unsigned short* HHp, unsigned short* HLp, float* ENC2Wp,
    int w, int lane)
{
    const int lc = lane & 15, lg = lane >> 4;
    f32x4 acc[NJT][2];
#pragma unroll
    for (int jj = 0; jj < NJT; ++jj)
#pragma unroll
        for (int rt = 0; rt < 2; ++rt)
            acc[jj][rt] = (f32x4){0.f, 0.f, 0.f, 0.f};

    __syncthreads();  // inputs ready
    for (int c = 0; c < KC; ++c) {
        const int boff = c * 32 + lg * 8;
        short8v bh0 = *(const short8v*)&HHp[lc * 264 + boff];
        short8v bl0 = *(const short8v*)&HLp[lc * 264 + boff];
        short8v bh1 = *(const short8v*)&HHp[(16 + lc) * 264 + boff];
        short8v bl1 = *(const short8v*)&HLp[(16 + lc) * 264 + boff];
#pragma unroll
        for (int jj = 0; jj < NJT; ++jj) {
            int fi = (((w * NJT + jj) * KC + c) * 2) * 64 + lane;
            short8v ah = Wf[fi];
            short8v al = Wf[fi + 64];
            acc[jj][0] = __builtin_amdgcn_mfma_f32_16x16x32_bf16(al, bh0, acc[jj][0], 0, 0, 0);
            acc[jj][0] = __builtin_amdgcn_mfma_f32_16x16x32_bf16(ah, bl0, acc[jj][0], 0, 0, 0);
            acc[jj][0] = __builtin_amdgcn_mfma_f32_16x16x32_bf16(ah, bh0, acc[jj][0], 0, 0, 0);
            acc[jj][1] = __builtin_amdgcn_mfma_f32_16x16x32_bf16(al, bh1, acc[jj][1], 0, 0, 0);
            acc[jj][1] = __builtin_amdgcn_mfma_f32_16x16x32_bf16(ah, bl1, acc[jj][1], 0, 0, 0);
            acc[jj][1] = __builtin_amdgcn_mfma_f32_16x16x32_bf16(ah, bh1, acc[jj][1], 0, 0, 0);
        }
    }
    __syncthreads();  // all reads done; in-place writes now safe

    float sq0 = 0.f, sq1 = 0.f;
#pragma unroll
    for (int jj = 0; jj < NJT; ++jj) {
        int j0 = (w * NJT + jj) * 16 + lg * 4;
        float4 bv = *(const float4*)&bias[j0];
        float bb[4] = {bv.x, bv.y, bv.z, bv.w};
#pragma unroll
        for (int rt = 0; rt < 2; ++rt) {
            int r = rt * 16 + lc;
            ushort4v hv, lv;
#pragma unroll
            for (int reg = 0; reg < 4; ++reg) {
                float v = acc[jj][rt][reg] + bb[reg];
                if (RELU) v = fmaxf(v, 0.f);
                if (SQSUM) { if (rt == 0) sq0 += v * v; else sq1 += v * v; }
                unsigned short h, l;
                split2(v, h, l);
                hv[reg] = h; lv[reg] = l;
            }
            *(ushort4v*)&HHp[r * 264 + j0] = hv;
            *(ushort4v*)&HLp[r * 264 + j0] = lv;
        }
    }
    if (SQSUM) {
        sq0 += __shfl_xor(sq0, 16); sq0 += __shfl_xor(sq0, 32);
        sq1 += __shfl_xor(sq1, 16); sq1 += __shfl_xor(sq1, 32);
        if (lg == 0) {
            ENC2Wp[w * 32 + lc] = sq0;
            ENC2Wp[w * 32 + 16 + lc] = sq1;
        }
    }
}

__global__ void vqvae_main_mfma(
    const float* __restrict__ action,
    const float* __restrict__ w1, const float* __restrict__ b1,
    const float* __restrict__ b2, const float* __restrict__ b3,
    const float* __restrict__ emb,
    const float* __restrict__ d1b, const float* __restrict__ d2b,
    const float* __restrict__ rb,
    float* __restrict__ out, float* __restrict__ ws)
{
    __shared__ __align__(16) unsigned short HH[32 * 264];
    __shared__ __align__(16) unsigned short HL[32 * 264];
    __shared__ float AT[6 * 32];
    __shared__ float E2S[512];
    __shared__ float TOPV[4][32][3];
    __shared__ float ENC2W[4 * 32];
    __shared__ int IDXR[32];
    __shared__ int FLAGR[32];
    __shared__ float RED[8];

    const int t = threadIdx.x;
    const int w = t >> 6, lane = t & 63;
    const int lc = lane & 15, lg = lane >> 4;
    const int row0 = blockIdx.x * 32;
    const unsigned short* wsb = (const unsigned short*)(ws + WS_SPLIT_F);
    const short8v* W2f = (const short8v*)wsb + OFF_W2 / 8;
    const short8v* W3f = (const short8v*)wsb + OFF_W3 / 8;
    const short8v* EMBf = (const short8v*)wsb + OFF_EMB / 8;
    const short8v* D1f = (const short8v*)wsb + OFF_D1 / 8;
    const short8v* D2f = (const short8v*)wsb + OFF_D2 / 8;
    const short8v* RWf = (const short8v*)wsb + OFF_RW / 8;

    // ---- stage action (transposed) + e2 ----
    if (t < 192) {
        int r = t / 6, i = t - r * 6;
        AT[i * 32 + r] = action[(size_t)row0 * 6 + t];
    }
    for (int i = t; i < 512; i += 256) E2S[i] = ws[WS_E2 + i];
    __syncthreads();

    // ---- enc1 (VALU fp32): h1[j=t][r=0..31] -> splits ----
    {
        float wr[6];
#pragma unroll
        for (int i = 0; i < 6; ++i) wr[i] = w1[t * 6 + i];
        float bb = b1[t];
        for (int r = 0; r < 32; ++r) {
            float s = bb;
#pragma unroll
            for (int i = 0; i < 6; ++i) s += wr[i] * AT[i * 32 + r];
            s = fmaxf(s, 0.f);
            unsigned short h, l;
            split2(s, h, l);
            HH[r * 264 + t] = h;
            HL[r * 264 + t] = l;
        }
    }

    // ---- enc2: 256 -> 256 relu ----
    mfma_mlp<4, 8, true, false>(W2f, b2, HH, HL, ENC2W, w, lane);
    // ---- mu: 256 -> 128, no relu, + per-row ||enc||^2 partials ----
    mfma_mlp<2, 8, false, true>(W3f, b3, HH, HL, ENC2W, w, lane);

    // ---- VQ: dd[r][k] = e2[k] - 2 * enc . emb_k  (A=enc LDS, B=emb frags) ----
    float lvq = 0.f, lrec = 0.f;
    {
        f32x4 vacc[8][2];
#pragma unroll
        for (int kt = 0; kt < 8; ++kt) {
            vacc[kt][0] = (f32x4){0.f, 0.f, 0.f, 0.f};
            vacc[kt][1] = (f32x4){0.f, 0.f, 0.f, 0.f};
        }
        __syncthreads();  // enc splits ready
        for (int c = 0; c < 4; ++c) {
            const int aoff = c * 32 + lg * 8;
            short8v ah0 = *(const short8v*)&HH[lc * 264 + aoff];
            short8v al0 = *(const short8v*)&HL[lc * 264 + aoff];
            short8v ah1 = *(const short8v*)&HH[(16 + lc) * 264 + aoff];
            short8v al1 = *(const short8v*)&HL[(16 + lc) * 264 + aoff];
#pragma unroll
            for (int kt = 0; kt < 8; ++kt) {
                int fi = (((w * 8 + kt) * 4 + c) * 2) * 64 + lane;
                short8v bh = EMBf[fi];
                short8v bl = EMBf[fi + 64];
                vacc[kt][0] = __builtin_amdgcn_mfma_f32_16x16x32_bf16(al0, bh, vacc[kt][0], 0, 0, 0);
                vacc[kt][0] = __builtin_amdgcn_mfma_f32_16x16x32_bf16(ah0, bl, vacc[kt][0], 0, 0, 0);
                vacc[kt][0] = __builtin_amdgcn_mfma_f32_16x16x32_bf16(ah0, bh, vacc[kt][0], 0, 0, 0);
                vacc[kt][1] = __builtin_amdgcn_mfma_f32_16x16x32_bf16(al1, bh, vacc[kt][1], 0, 0, 0);
                vacc[kt][1] = __builtin_amdgcn_mfma_f32_16x16x32_bf16(ah1, bl, vacc[kt][1], 0, 0, 0);
                vacc[kt][1] = __builtin_amdgcn_mfma_f32_16x16x32_bf16(ah1, bh, vacc[kt][1], 0, 0, 0);
            }
        }
        __syncthreads();  // VQ reads of HH/HL done

        // top-2 per row-slot (rt, reg): scan own 8 kt, then merge across 16-lane col group
        float bv1[2][4], bv2[2][4];
        int bk1[2][4];
#pragma unroll
        for (int rt = 0; rt < 2; ++rt)
#pragma unroll
            for (int reg = 0; reg < 4; ++reg) {
                float v1 = 1e30f, v2 = 1e30f; int k1 = 0;
#pragma unroll
                for (int kt = 0; kt < 8; ++kt) {
                    int k = (w * 8 + kt) * 16 + lc;
                    float dd = E2S[k] - 2.f * vacc[kt][rt][reg];
                    if (dd < v1) { v2 = v1; v1 = dd; k1 = k; }
                    else if (dd < v2) v2 = dd;
                }
                bv1[rt][reg] = v1; bv2[rt][reg] = v2; bk1[rt][reg] = k1;
            }
#pragma unroll
        for (int m = 1; m < 16; m <<= 1) {
#pragma unroll
            for (int rt = 0; rt < 2; ++rt)
#pragma unroll
                for (int reg = 0; reg < 4; ++reg) {
                    float ov1 = __shfl_xor(bv1[rt][reg], m);
                    int ok1 = __shfl_xor(bk1[rt][reg], m);
                    float ov2 = __shfl_xor(bv2[rt][reg], m);
                    if (ov1 < bv1[rt][reg] ||
                        (ov1 == bv1[rt][reg] && ok1 < bk1[rt][reg])) {
                        bv2[rt][reg] = fminf(bv1[rt][reg], ov2);
                        bv1[rt][reg] = ov1; bk1[rt][reg] = ok1;
                    } else {
                        bv2[rt][reg] = fminf(bv2[rt][reg], ov1);
                    }
                }
        }
        if (lc == 0) {
#pragma unroll
            for (int rt = 0; rt < 2; ++rt)
#pragma unroll
                for (int reg = 0; reg < 4; ++reg) {
                    int row = rt * 16 + lg * 4 + reg;
                    TOPV[w][row][0] = bv1[rt][reg];
                    TOPV[w][row][1] = __int_as_float(bk1[rt][reg]);
                    TOPV[w][row][2] = bv2[rt][reg];
                }
        }
    }
    __syncthreads();

    // ---- merge 4 wave candidates; idx out, flag, lvq via ||enc-q||^2 = enc2 + dd_min ----
    if (t < 32) {
        float v1 = 1e30f, v2 = 1e30f; int k1 = 0;
#pragma unroll
        for (int ww = 0; ww < 4; ++ww) {
            float ov1 = TOPV[ww][t][0];
            int ok1 = __float_as_int(TOPV[ww][t][1]);
            float ov2 = TOPV[ww][t][2];
            if (ov1 < v1 || (ov1 == v1 && ok1 < k1)) {
                v2 = fminf(v1, ov2); v1 = ov1; k1 = ok1;
            } else {
                v2 = fminf(v2, ov1);
            }
        }
        int flag = (v2 - v1 >= MARGINF) ? 0 : 1;  // NaN-safe
        IDXR[t] = k1;
        FLAGR[t] = flag;
        int row = row0 + t;
        if (flag)
            atomicOr((unsigned int*)ws + WS_MASK + (row >> 5), 1u << (row & 31));
        out[row] = (float)k1;
        if (!flag) {
            float enc2 = ENC2W[0 * 32 + t] + ENC2W[1 * 32 + t] +
                         ENC2W[2 * 32 + t] + ENC2W[3 * 32 + t];
            lvq = enc2 + v1;
        }
    }
    __syncthreads();

    // ---- gather q (exact fp32), write q_st, split q -> HH/HL for decoder ----
    {
        int d = t & 127, half = t >> 7;
#pragma unroll
        for (int e = 0; e < 16; ++e) {
            int r = half * 16 + e;
            int k1 = IDXR[r];
            float q = emb[(size_t)k1 * 128 + d];
            out[NB + (size_t)(row0 + r) * 128 + d] = q;
            unsigned short h, l;
            split2(q, h, l);
            HH[r * 264 + d] = h;
            HL[r * 264 + d] = l;
        }
    }

    // ---- decoder ----
    mfma_mlp<4, 4, true, false>(D1f, d1b, HH, HL, ENC2W, w, lane);
    mfma_mlp<4, 8, true, false>(D2f, d2b, HH, HL, ENC2W, w, lane);
    __syncthreads();  // dec2 splits ready

    // ---- rec: 16(pad6) x 256 via MFMA on waves 0,1 ----
    if (w < 2) {
        f32x4 racc = (f32x4){0.f, 0.f, 0.f, 0.f};
        for (int c = 0; c < 8; ++c) {
            const int boff = c * 32 + lg * 8;
            short8v bh = *(const short8v*)&HH[(w * 16 + lc) * 264 + boff];
            short8v bl = *(const short8v*)&HL[(w * 16 + lc) * 264 + boff];
            int fi = (c * 2) * 64 + lane;
            short8v ah = RWf[fi];
            short8v al = RWf[fi + 64];
            racc = __builtin_amdgcn_mfma_f32_16x16x32_bf16(al, bh, racc, 0, 0, 0);
            racc = __builtin_amdgcn_mfma_f32_16x16x32_bf16(ah, bl, racc, 0, 0, 0);
            racc = __builtin_amdgcn_mfma_f32_16x16x32_bf16(ah, bh, racc, 0, 0, 0);
        }
        int r = w * 16 + lc;
#pragma unroll
        for (int reg = 0; reg < 4; ++reg) {
            int j = lg * 4 + reg;
            if (j < 6) {
                float rec = tanhf(racc[reg] + rb[j]);
                float df = rec - AT[j * 32 + r];
                if (!FLAGR[r]) lrec += df * df;
            }
        }
    }

    // ---- block loss reduction -> global double atomics ----
#pragma unroll
    for (int m = 1; m < 64; m <<= 1) {
        lvq += __shfl_xor(lvq, m);
        lrec += __shfl_xor(lrec, m);
    }
    if ((t & 63) == 0) { RED[t >> 6] = lvq; RED[4 + (t >> 6)] = lrec; }
    __syncthreads();
    if (t == 0) {
        atomicAdd((double*)ws + 0, (double)((RED[0] + RED[1]) + (RED[2] + RED[3])));
        atomicAdd((double*)ws + 1, (double)((RED[4] + RED[5]) + (RED[6] + RED[7])));
    }
}

// ---------------- fp32 fallback (round-4, verified) ----------------
static __device__ __forceinline__ void gemm_out256(
    const float* __restrict__ W, const float* __restrict__ bias, int IN,
    const float* __restrict__ hin, float* __restrict__ hout,
    float* __restrict__ WC, int t, int tx, int r0, bool do_relu)
{
    float acc[2][4][4];
#pragma unroll
    for (int g = 0; g < 2; ++g)
#pragma unroll
        for (int a = 0; a < 4; ++a)
#pragma unroll
            for (int b = 0; b < 4; ++b) acc[g][a][b] = 0.f;
    float4 pa = *(const float4*)(W + (size_t)t * IN);
    float4 pb = *(const float4*)(W + (size_t)t * IN + 4);
    for (int i0 = 0; i0 < IN; i0 += 8) {
        __syncthreads();
        WC[0 * 256 + t] = pa.x; WC[1 * 256 + t] = pa.y;
        WC[2 * 256 + t] = pa.z; WC[3 * 256 + t] = pa.w;
        WC[4 * 256 + t] = pb.x; WC[5 * 256 + t] = pb.y;
        WC[6 * 256 + t] = pb.z; WC[7 * 256 + t] = pb.w;
        __syncthreads();
        if (i0 + 8 < IN) {
            pa = *(const float4*)(W + (size_t)t * IN + i0 + 8);
            pb = *(const float4*)(W + (size_t)t * IN + i0 + 12);
        }
#pragma unroll
        for (int i = 0; i < 8; ++i) {
            int row = i0 + i;
            float4 h = *(const float4*)&hin[row * 32 + (r0 ^ SWC(row))];
            float4 w0 = *(const float4*)&WC[i * 256 + 4 * tx];
            float4 w1v = *(const float4*)&WC[i * 256 + 128 + 4 * tx];
            float wv0[4] = {w0.x, w0.y, w0.z, w0.w};
            float wv1[4] = {w1v.x, w1v.y, w1v.z, w1v.w};
            float hv[4] = {h.x, h.y, h.z, h.w};
#pragma unroll
            for (int a = 0; a < 4; ++a)
#pragma unroll
                for (int b = 0; b < 4; ++b) {
                    acc[0][a][b] += wv0[a] * hv[b];
                    acc[1][a][b] += wv1[a] * hv[b];
                }
        }
    }
#pragma unroll
    for (int g = 0; g < 2; ++g)
#pragma unroll
        for (int a = 0; a < 4; ++a) {
            int j = g * 128 + 4 * tx + a;
            float bj = bias[j];
            float4 v;
            v.x = acc[g][a][0] + bj; v.y = acc[g][a][1] + bj;
            v.z = acc[g][a][2] + bj; v.w = acc[g][a][3] + bj;
            if (do_relu) {
                v.x = fmaxf(v.x, 0.f); v.y = fmaxf(v.y, 0.f);
                v.z = fmaxf(v.z, 0.f); v.w = fmaxf(v.w, 0.f);
            }
            *(float4*)&hout[j * 32 + (r0 ^ SWC(j))] = v;
        }
    __syncthreads();
}

__global__ __launch_bounds__(256, 2) void vqvae_main_fp32(
    const float* __restrict__ action,
    const float* __restrict__ w1, const float* __restrict__ b1,
    const float* __restrict__ w2, const float* __restrict__ b2,
    const float* __restrict__ w3, const float* __restrict__ b3,
    const float* __restrict__ emb,
    const float* __restrict__ d1w, const float* __restrict__ d1b,
    const float* __restrict__ d2w, const float* __restrict__ d2b,
    const float* __restrict__ rw, const float* __restrict__ rb,
    float* __restrict__ out, float* __restrict__ ws)
{
    __shared__ float X[256 * 32];
    __shared__ float Y[256 * 32];
    __shared__ float WC[2048];
    __shared__ float AT[6 * 32];
    __shared__ int IDXR[32];
    __shared__ int FLAGR[32];
    __shared__ float RED[8];

    const int t = threadIdx.x;
    const int tx = t & 31, ty = t >> 5;
    const int r0 = ty * 4;
    const int row0 = blockIdx.x * 32;

    if (t < 192) {
        int r = t / 6, i = t - r * 6;
        AT[i * 32 + r] = action[(size_t)row0 * 6 + t];
    }
    __syncthreads();
    {
#pragma unroll
        for (int i = 0; i < 6; ++i) WC[i * 256 + t] = w1[t * 6 + i];
        __syncthreads();
        float acc[2][4][4];
#pragma unroll
        for (int g = 0; g < 2; ++g)
#pragma unroll
            for (int a = 0; a < 4; ++a)
#pragma unroll
                for (int b = 0; b < 4; ++b) acc[g][a][b] = 0.f;
#pragma unroll
        for (int i = 0; i < 6; ++i) {
            float4 h = *(const float4*)&AT[i * 32 + r0];
            float4 w0 = *(const float4*)&WC[i * 256 + 4 * tx];
            float4 w1v = *(const float4*)&WC[i * 256 + 128 + 4 * tx];
            float wv0[4] = {w0.x, w0.y, w0.z, w0.w};
            float wv1[4] = {w1v.x, w1v.y, w1v.z, w1v.w};
            float hv[4] = {h.x, h.y, h.z, h.w};
#pragma unroll
            for (int a = 0; a < 4; ++a)
#pragma unroll
                for (int b = 0; b < 4; ++b) {
                    acc[0][a][b] += wv0[a] * hv[b];
                    acc[1][a][b] += wv1[a] * hv[b];
                }
        }
#pragma unroll
        for (int g = 0; g < 2; ++g)
#pragma unroll
            for (int a = 0; a < 4; ++a) {
                int j = g * 128 + 4 * tx + a;
                float bj = b1[j];
                float4 v;
                v.x = fmaxf(acc[g][a][0] + bj, 0.f);
                v.y = fmaxf(acc[g][a][1] + bj, 0.f);
                v.z = fmaxf(acc[g][a][2] + bj, 0.f);
                v.w = fmaxf(acc[g][a][3] + bj, 0.f);
                *(float4*)&X[j * 32 + (r0 ^ SWC(j))] = v;
            }
        __syncthreads();
    }
    gemm_out256(w2, b2, 256, X, Y, WC, t, tx, r0, true);
    {
        float acc[4][4];
#pragma unroll
        for (int a = 0; a < 4; ++a)
#pragma unroll
            for (int b = 0; b < 4; ++b) acc[a][b] = 0.f;
        float4 pa, pb;
        if (t < 128) {
            pa = *(const float4*)(w3 + (size_t)t * 256);
            pb = *(const float4*)(w3 + (size_t)t * 256 + 4);
        }
        for (int i0 = 0; i0 < 256; i0 += 8) {
            __syncthreads();
            if (t < 128) {
                WC[0 * 128 + t] = pa.x; WC[1 * 128 + t] = pa.y;
                WC[2 * 128 + t] = pa.z; WC[3 * 128 + t] = pa.w;
                WC[4 * 128 + t] = pb.x; WC[5 * 128 + t] = pb.y;
                WC[6 * 128 + t] = pb.z; WC[7 * 128 + t] = pb.w;
            }
            __syncthreads();
            if (t < 128 && i0 + 8 < 256) {
                pa = *(const float4*)(w3 + (size_t)t * 256 + i0 + 8);
                pb = *(const float4*)(w3 + (size_t)t * 256 + i0 + 12);
            }
#pragma unroll
            for (int i = 0; i < 8; ++i) {
                int row = i0 + i;
                float4 h = *(const float4*)&Y[row * 32 + (r0 ^ SWC(row))];
                float4 w0 = *(const float4*)&WC[i * 128 + 4 * tx];
                float wv[4] = {w0.x, w0.y, w0.z, w0.w};
                float hv[4] = {h.x, h.y, h.z, h.w};
#pragma unroll
                for (int a = 0; a < 4; ++a)
#pragma unroll
                    for (int b = 0; b < 4; ++b) acc[a][b] += wv[a] * hv[b];
            }
        }
#pragma unroll
        for (int a = 0; a < 4; ++a) {
            int j = 4 * tx + a;
            float bj = b3[j];
            float4 v;
            v.x = acc[a][0] + bj; v.y = acc[a][1] + bj;
            v.z = acc[a][2] + bj; v.w = acc[a][3] + bj;
            *(float4*)&X[j * 32 + (r0 ^ SWC(j))] = v;
        }
        __syncthreads();
    }
    {
        float bv1[4], bv2[4];
        int bk1[4];
        float acc[4][4][4];
#pragma unroll
        for (int p = 0; p < 4; ++p)
#pragma unroll
            for (int a = 0; a < 4; ++a)
#pragma unroll
                for (int b = 0; b < 4; ++b) acc[p][a][b] = 0.f;
        float4 qa = *(const float4*)(emb + (size_t)t * 128);
        float4 qb = *(const float4*)(emb + (size_t)(t + 256) * 128);
        for (int d0 = 0; d0 < 128; d0 += 4) {
            __syncthreads();
            WC[0 * 512 + t] = qa.x; WC[1 * 512 + t] = qa.y;
            WC[2 * 512 + t] = qa.z; WC[3 * 512 + t] = qa.w;
            WC[0 * 512 + 256 + t] = qb.x; WC[1 * 512 + 256 + t] = qb.y;
            WC[2 * 512 + 256 + t] = qb.z; WC[3 * 512 + 256 + t] = qb.w;
            __syncthreads();
            if (d0 + 4 < 128) {
                qa = *(const float4*)(emb + (size_t)t * 128 + d0 + 4);
                qb = *(const float4*)(emb + (size_t)(t + 256) * 128 + d0 + 4);
            }
#pragma unroll
            for (int i = 0; i < 4; ++i) {
                int row = d0 + i;
                float4 h = *(const float4*)&X[row * 32 + (r0 ^ SWC(row))];
                float hv[4] = {h.x, h.y, h.z, h.w};
#pragma unroll
                for (int p = 0; p < 4; ++p) {
                    float4 w0 = *(const float4*)&WC[i * 512 + p * 128 + 4 * tx];
                    float wv[4] = {w0.x, w0.y, w0.z, w0.w};
#pragma unroll
                    for (int a = 0; a < 4; ++a)
#pragma unroll
                        for (int b = 0; b < 4; ++b) acc[p][a][b] += wv[a] * hv[b];
                }
            }
        }
#pragma unroll
        for (int b = 0; b < 4; ++b) { bv1[b] = 1e30f; bv2[b] = 1e30f; bk1[b] = 0; }
#pragma unroll
        for (int p = 0; p < 4; ++p)
#pragma unroll
            for (int a = 0; a < 4; ++a) {
                int k = p * 128 + 4 * tx + a;
                float ek = ws[WS_E2 + k];
#pragma unroll
                for (int b = 0; b < 4; ++b) {
                    float dd = ek - 2.f * acc[p][a][b];
                    if (dd < bv1[b]) { bv2[b] = bv1[b]; bv1[b] = dd; bk1[b] = k; }
                    else if (dd < bv2[b]) bv2[b] = dd;
                }
            }
#pragma unroll
        for (int m = 1; m < 32; m <<= 1) {
#pragma unroll
            for (int b = 0; b < 4; ++b) {
                float ov1 = __shfl_xor(bv1[b], m);
                int ok1 = __shfl_xor(bk1[b], m);
                float ov2 = __shfl_xor(bv2[b], m);
                if (ov1 < bv1[b] || (ov1 == bv1[b] && ok1 < bk1[b])) {
                    bv2[b] = fminf(bv1[b], ov2);
                    bv1[b] = ov1; bk1[b] = ok1;
                } else {
                    bv2[b] = fminf(bv2[b], ov1);
                }
            }
        }
        if (tx == 0) {
#pragma unroll
            for (int b = 0; b < 4; ++b) {
                IDXR[r0 + b] = bk1[b];
                FLAGR[r0 + b] = (bv2[b] - bv1[b] >= MARGINF) ? 0 : 1;
            }
        }
    }
    __syncthreads();
    if (t < 32) {
        int row = row0 + t;
        if (FLAGR[t])
            atomicOr((unsigned int*)ws + WS_MASK + (row >> 5), 1u << (row & 31));
        out[row] = (float)IDXR[t];
    }
    float lvq = 0.f, lrec = 0.f;
    {
        int d = t & 127, rq = t >> 7;
        int cd = SWC(d);
#pragma unroll
        for (int e = 0; e < 4; ++e) {
            int rr = (rq + 2 * e) * 4;
            float4 en = *(const float4*)&X[d * 32 + (rr ^ cd)];
            float q0 = emb[(size_t)IDXR[rr + 0] * 128 + d];
            float q1 = emb[(size_t)IDXR[rr + 1] * 128 + d];
            float q2 = emb[(size_t)IDXR[rr + 2] * 128 + d];
            float q3 = emb[(size_t)IDXR[rr + 3] * 128 + d];
            float4 qv; qv.x = q0; qv.y = q1; qv.z = q2; qv.w = q3;
            *(float4*)&X[(128 + d) * 32 + (rr ^ cd)] = qv;
            if (!FLAGR[rr + 0]) lvq += (en.x - q0) * (en.x - q0);
            if (!FLAGR[rr + 1]) lvq += (en.y - q1) * (en.y - q1);
            if (!FLAGR[rr + 2]) lvq += (en.z - q2) * (en.z - q2);
            if (!FLAGR[rr + 3]) lvq += (en.w - q3) * (en.w - q3);
            out[NB + (size_t)(row0 + rr + 0) * 128 + d] = q0;
            out[NB + (size_t)(row0 + rr + 1) * 128 + d] = q1;
            out[NB + (size_t)(row0 + rr + 2) * 128 + d] = q2;
            out[NB + (size_t)(row0 + rr + 3) * 128 + d] = q3;
        }
    }
    __syncthreads();
    gemm_out256(d1w, d1b, 128, X + 128 * 32, Y, WC, t, tx, r0, true);
    gemm_out256(d2w, d2b, 256, Y, X, WC, t, tx, r0, true);
    if (t < 192) {
        int jj = t >> 5, r = t & 31;
        const float* wr = rw + jj * 256;
        float a0 = 0.f, a1 = 0.f, a2 = 0.f, a3 = 0.f;
        for (int i = 0; i < 256; i += 4) {
            a0 += wr[i] * X[i * 32 + (r ^ SWC(i))];
            a1 += wr[i + 1] * X[(i + 1) * 32 + (r ^ SWC(i + 1))];
            a2 += wr[i + 2] * X[(i + 2) * 32 + (r ^ SWC(i + 2))];
            a3 += wr[i + 3] * X[(i + 3) * 32 + (r ^ SWC(i + 3))];
        }
        float rec = tanhf(rb[jj] + (a0 + a1) + (a2 + a3));
        float df = rec - AT[jj * 32 + r];
        if (!FLAGR[r]) lrec = df * df;
    }
#pragma unroll
    for (int m = 1; m < 64; m <<= 1) {
        lvq += __shfl_xor(lvq, m);
        lrec += __shfl_xor(lrec, m);
    }
    if ((t & 63) == 0) { RED[t >> 6] = lvq; RED[4 + (t >> 6)] = lrec; }
    __syncthreads();
    if (t == 0) {
        atomicAdd((double*)ws + 0, (double)((RED[0] + RED[1]) + (RED[2] + RED[3])));
        atomicAdd((double*)ws + 1, (double)((RED[4] + RED[5]) + (RED[6] + RED[7])));
    }
}

// ---------------- fp64 repair of ambiguous rows (unchanged, verified) ----------------
__global__ __launch_bounds__(256) void vqvae_fix(
    const float* __restrict__ action,
    const float* __restrict__ w1, const float* __restrict__ b1,
    const float* __restrict__ w2, const float* __restrict__ b2,
    const float* __restrict__ w3, const float* __restrict__ b3,
    const float* __restrict__ emb,
    const float* __restrict__ d1w, const float* __restrict__ d1b,
    const float* __restrict__ d2w, const float* __restrict__ d2b,
    const float* __restrict__ rw, const float* __restrict__ rb,
    float* __restrict__ out, float* __restrict__ ws)
{
    __shared__ double H1[256];
    __shared__ double H2[256];
    __shared__ double ENC[128];
    __shared__ double QD[128];
    __shared__ double SRED[256];
    __shared__ int SK[256];
    __shared__ double SA[6];

    const int t = threadIdx.x;
    const unsigned int word = ((const unsigned int*)ws)[WS_MASK + blockIdx.x];
    if (word == 0u) return;

    for (int bit = 0; bit < 32; ++bit) {
        if (!(word & (1u << bit))) continue;
        const int row = (blockIdx.x << 5) + bit;

        if (t < 6) SA[t] = (double)action[(size_t)row * 6 + t];
        __syncthreads();
        {
            double a = (double)b1[t];
#pragma unroll
            for (int i = 0; i < 6; ++i) a += (double)w1[t * 6 + i] * SA[i];
            H1[t] = a > 0.0 ? a : 0.0;
        }
        __syncthreads();
        {
            const float* w = w2 + (size_t)t * 256;
            double a0 = 0, a1 = 0, a2 = 0, a3 = 0;
            for (int i = 0; i < 256; i += 4) {
                a0 += (double)w[i] * H1[i];     a1 += (double)w[i + 1] * H1[i + 1];
                a2 += (double)w[i + 2] * H1[i + 2]; a3 += (double)w[i + 3] * H1[i + 3];
            }
            double a = (double)b2[t] + a0 + a1 + a2 + a3;
            H2[t] = a > 0.0 ? a : 0.0;
        }
        __syncthreads();
        if (t < 128) {
            const float* w = w3 + (size_t)t * 256;
            double a0 = 0, a1 = 0, a2 = 0, a3 = 0;
            for (int i = 0; i < 256; i += 4) {
                a0 += (double)w[i] * H2[i];     a1 += (double)w[i + 1] * H2[i + 1];
                a2 += (double)w[i + 2] * H2[i + 2]; a3 += (double)w[i + 3] * H2[i + 3];
            }
            ENC[t] = (double)b3[t] + a0 + a1 + a2 + a3;
        }
        __syncthreads();
        double best = 1e300; int bk = 0;
#pragma unroll
        for (int kk = 0; kk < 2; ++kk) {
            int k = t + kk * 256;
            const float* e = emb + (size_t)k * 128;
            double s0 = 0, s1 = 0;
            for (int d = 0; d < 128; d += 2) {
                double df0 = ENC[d] - (double)e[d];
                double df1 = ENC[d + 1] - (double)e[d + 1];
                s0 += df0 * df0; s1 += df1 * df1;
            }
            double s = s0 + s1;
            if (s < best) { best = s; bk = k; }
        }
        SRED[t] = best; SK[t] = bk;
        __syncthreads();
        for (int st = 128; st > 0; st >>= 1) {
            if (t < st) {
                double ov = SRED[t + st]; int ok = SK[t + st];
                if (ov < SRED[t] || (ov == SRED[t] && ok < SK[t])) { SRED[t] = ov; SK[t] = ok; }
            }
            __syncthreads();
        }
        const int bestk = SK[0];
        double lv = 0.0;
        if (t < 128) {
            double q = (double)emb[(size_t)bestk * 128 + t];
            QD[t] = q;
            double df = ENC[t] - q;
            lv = df * df;
            out[NB + (size_t)row * 128 + t] = (float)q;
        }
        if (t == 0) out[row] = (float)bestk;
        __syncthreads();
        {
            const float* w = d1w + (size_t)t * 128;
            double a0 = 0, a1 = 0;
            for (int i = 0; i < 128; i += 2) {
                a0 += (double)w[i] * QD[i]; a1 += (double)w[i + 1] * QD[i + 1];
            }
            double a = (double)d1b[t] + a0 + a1;
            H1[t] = a > 0.0 ? a : 0.0;
        }
        __syncthreads();
        {
            const float* w = d2w + (size_t)t * 256;
            double a0 = 0, a1 = 0, a2 = 0, a3 = 0;
            for (int i = 0; i < 256; i += 4) {
                a0 += (double)w[i] * H1[i];     a1 += (double)w[i + 1] * H1[i + 1];
                a2 += (double)w[i + 2] * H1[i + 2]; a3 += (double)w[i + 3] * H1[i + 3];
            }
            double a = (double)d2b[t] + a0 + a1 + a2 + a3;
            H2[t] = a > 0.0 ? a : 0.0;
        }
        __syncthreads();
        double lr = 0.0;
        if (t < 6) {
            const float* w = rw + (size_t)t * 256;
            double a0 = 0, a1 = 0;
            for (int i = 0; i < 256; i += 2) {
                a0 += (double)w[i] * H2[i]; a1 += (double)w[i + 1] * H2[i + 1];
            }
            double rec = tanh((double)rb[t] + a0 + a1);
            double df = rec - SA[t];
            lr = df * df;
        }
        SRED[t] = lv;
        __syncthreads();
        for (int st = 128; st > 0; st >>= 1) {
            if (t < st) SRED[t] += SRED[t + st];
            __syncthreads();
        }
        if (t == 0) atomicAdd((double*)ws + 0, SRED[0]);
        if (t < 6) atomicAdd((double*)ws + 1, lr);
        __syncthreads();
    }
}

__global__ void vqvae_fin(const float* __restrict__ ws, float* __restrict__ out) {
    if (threadIdx.x == 0 && blockIdx.x == 0) {
        const double* D = (const double*)ws;
        double loss = D[1] / ((double)NB * 6.0) + 1.25 * (D[0] / ((double)NB * 128.0));
        out[(size_t)NB * 129] = (float)loss;
    }
}

extern "C" void kernel_launch(void* const* d_in, const int* in_sizes, int n_in,
                              void* d_out, int out_size, void* d_ws, size_t ws_size,
                              hipStream_t stream) {
    const float* action = (const float*)d_in[0];
    const float* w1 = (const float*)d_in[1];
    const float* b1 = (const float*)d_in[2];
    const float* w2 = (const float*)d_in[3];
    const float* b2 = (const float*)d_in[4];
    const float* w3 = (const float*)d_in[5];
    const float* b3 = (const float*)d_in[6];
    const float* emb = (const float*)d_in[7];
    const float* d1w = (const float*)d_in[8];
    const float* d1b = (const float*)d_in[9];
    const float* d2w = (const float*)d_in[10];
    const float* d2b = (const float*)d_in[11];
    const float* rw = (const float*)d_in[12];
    const float* rb = (const float*)d_in[13];
    float* out = (float*)d_out;
    float* ws = (float*)d_ws;

    const size_t need_mfma = (size_t)WS_BASE_BYTES + (size_t)SPLIT_TOTAL * 2;
    const int use_mfma = (ws_size >= need_mfma) ? 1 : 0;

    size_t clear = ws_size < (size_t)WS_BASE_BYTES ? ws_size : (size_t)WS_BASE_BYTES;
    hipMemsetAsync(d_ws, 0, clear, stream);

    prep_kernel<<<1043, 256, 0, stream>>>(w2, w3, emb, d1w, d2w, rw, ws, use_mfma);
    if (use_mfma) {
        vqvae_main_mfma<<<NB / 32, 256, 0, stream>>>(action, w1, b1, b2, b3, emb,
                                                     d1b, d2b, rb, out, ws);
    } else {
        vqvae_main_fp32<<<NB / 32, 256, 0, stream>>>(action, w1, b1, w2, b2, w3, b3, emb,
                                                     d1w, d1b, d2w, d2b, rw, rb, out, ws);
    }
    vqvae_fix<<<NB / 32, 256, 0, stream>>>(action, w1, b1, w2, b2, w3, b3, emb,
                                           d1w, d1b, d2w, d2b, rw, rb, out, ws);
    vqvae_fin<<<1, 64, 0, stream>>>(ws, out);
}

// Round 6
// 480.282 us; speedup vs baseline: 2.9798x; 1.3852x over previous
//
#include <hip/hip_runtime.h>
#include <hip/hip_bf16.h>

#define NB 131072
#define MARGINF 2e-6f
// ws layout: doubles[128] at float idx 0..255 (vq slots 0..63, rec slots 64..127);
// e2[512] at float idx 256..767; bitmask u32[4096] at word idx 768..4863;
// bf16 split-weight region from float idx 4864.
#define WS_E2 256
#define WS_MASK 768
#define WS_MASKW 4096
#define WS_BASE_BYTES ((768 + 4096) * 4)
#define WS_SPLIT_F 4864
// split region offsets (bf16 element units, relative to split base)
#define OFF_W2 0
#define OFF_W3 131072
#define OFF_EMB 196608
#define OFF_D1 327680
#define OFF_D2 393216
#define OFF_RW 524288
#define SPLIT_TOTAL 532480

typedef __attribute__((ext_vector_type(8))) short short8v;
typedef __attribute__((ext_vector_type(4))) float f32x4;
typedef __attribute__((ext_vector_type(4))) unsigned short ushort4v;

#define SWC(j) ((((j) >> 2) & 7) << 2)

__device__ __forceinline__ unsigned short bf16rn(float x) {
    unsigned u = __float_as_uint(x);
    unsigned r = u + 0x7fffu + ((u >> 16) & 1u);
    return (unsigned short)(r >> 16);
}
__device__ __forceinline__ void split2(float x, unsigned short& h, unsigned short& l) {
    h = bf16rn(x);
    float hf = __uint_as_float((unsigned)h << 16);
    l = bf16rn(x - hf);
}

// ---------------- prep: e2 + fragment-linear bf16 weight splits ----------------
__global__ void prep_kernel(
    const float* __restrict__ w2, const float* __restrict__ w3,
    const float* __restrict__ emb, const float* __restrict__ d1w,
    const float* __restrict__ d2w, const float* __restrict__ rw,
    float* __restrict__ ws, int do_splits)
{
    const int total = 512 + 266240;
    unsigned short* wsb = (unsigned short*)(ws + WS_SPLIT_F);
    for (int idx = blockIdx.x * 256 + threadIdx.x; idx < total; idx += gridDim.x * 256) {
        if (idx < 512) {
            const float* e = emb + (size_t)idx * 128;
            float s0 = 0.f, s1 = 0.f, s2 = 0.f, s3 = 0.f;
            for (int d = 0; d < 128; d += 4) {
                s0 += e[d] * e[d];     s1 += e[d + 1] * e[d + 1];
                s2 += e[d + 2] * e[d + 2]; s3 += e[d + 3] * e[d + 3];
            }
            ws[WS_E2 + idx] = (s0 + s1) + (s2 + s3);
            continue;
        }
        if (!do_splits) continue;
        int j = idx - 512;
        int base, K, o, k;
        float src;
        if (j < 65536) {            // w2: 256x256
            o = j >> 8; k = j & 255; base = OFF_W2; K = 256; src = w2[o * 256 + k];
        } else if (j < 98304) {     // w3: 128x256
            j -= 65536; o = j >> 8; k = j & 255; base = OFF_W3; K = 256; src = w3[o * 256 + k];
        } else if (j < 163840) {    // emb: 512x128
            j -= 98304; o = j >> 7; k = j & 127; base = OFF_EMB; K = 128; src = emb[o * 128 + k];
        } else if (j < 196608) {    // d1w: 256x128
            j -= 163840; o = j >> 7; k = j & 127; base = OFF_D1; K = 128; src = d1w[o * 128 + k];
        } else if (j < 262144) {    // d2w: 256x256
            j -= 196608; o = j >> 8; k = j & 255; base = OFF_D2; K = 256; src = d2w[o * 256 + k];
        } else {                    // rw padded to 16 rows: 16x256
            j -= 262144; o = j >> 8; k = j & 255; base = OFF_RW; K = 256;
            src = (o < 6) ? rw[o * 256 + k] : 0.f;
        }
        unsigned short h, l;
        split2(src, h, l);
        int jt = o >> 4, c = k >> 5;
        int lane = (((k >> 3) & 3) << 4) | (o & 15);
        int e = k & 7;
        int a = base + ((jt * (K >> 5) + c) * 2) * 512 + lane * 8 + e;
        wsb[a] = h;
        wsb[a + 512] = l;
    }
}

// ---------------- MFMA main kernel: 64 rows/block, 4 waves ----------------
// Activations hi/lo bf16 in dynamic LDS [64 rows][264]. Weight frags from ws (L2).

template<int NJT, int KC, bool RELU, bool SQSUM>
__device__ __forceinline__ void mfma_mlp4(
    const short8v* __restrict__ Wf, const float* __restrict__ bias,
    unsigned short* HHp, unsigned short* HLp, float* ENC2Wp,
    int w, int lane)
{
    const int lc = lane & 15, lg = lane >> 4;
    f32x4 acc[NJT][4];
#pragma unroll
    for (int jj = 0; jj < NJT; ++jj)
#pragma unroll
        for (int rt = 0; rt < 4; ++rt)
            acc[jj][rt] = (f32x4){0.f, 0.f, 0.f, 0.f};

    __syncthreads();  // inputs ready
    for (int c = 0; c < KC; ++c) {
        const int boff = c * 32 + lg * 8;
        short8v bh[4], bl[4];
#pragma unroll
        for (int rt = 0; rt < 4; ++rt) {
            bh[rt] = *(const short8v*)&HHp[(rt * 16 + lc) * 264 + boff];
            bl[rt] = *(const short8v*)&HLp[(rt * 16 + lc) * 264 + boff];
        }
#pragma unroll
        for (int jj = 0; jj < NJT; ++jj) {
            int fi = (((w * NJT + jj) * KC + c) * 2) * 64 + lane;
            short8v ah = Wf[fi];
            short8v al = Wf[fi + 64];
#pragma unroll
            for (int rt = 0; rt < 4; ++rt) {
                acc[jj][rt] = __builtin_amdgcn_mfma_f32_16x16x32_bf16(al, bh[rt], acc[jj][rt], 0, 0, 0);
                acc[jj][rt] = __builtin_amdgcn_mfma_f32_16x16x32_bf16(ah, bl[rt], acc[jj][rt], 0, 0, 0);
                acc[jj][rt] = __builtin_amdgcn_mfma_f32_16x16x32_bf16(ah, bh[rt], acc[jj][rt], 0, 0, 0);
            }
        }
    }
    __syncthreads();  // all reads done; in-place writes now safe

    float sq[4] = {0.f, 0.f, 0.f, 0.f};
#pragma unroll
    for (int jj = 0; jj < NJT; ++jj) {
        int j0 = (w * NJT + jj) * 16 + lg * 4;
        float4 bv = *(const float4*)&bias[j0];
        float bb[4] = {bv.x, bv.y, bv.z, bv.w};
#pragma unroll
        for (int rt = 0; rt < 4; ++rt) {
            int r = rt * 16 + lc;
            ushort4v hv, lv;
#pragma unroll
            for (int reg = 0; reg < 4; ++reg) {
                float v = acc[jj][rt][reg] + bb[reg];
                if (RELU) v = fmaxf(v, 0.f);
                if (SQSUM) sq[rt] += v * v;
                unsigned short h, l;
                split2(v, h, l);
                hv[reg] = h; lv[reg] = l;
            }
            *(ushort4v*)&HHp[r * 264 + j0] = hv;
            *(ushort4v*)&HLp[r * 264 + j0] = lv;
        }
    }
    if (SQSUM) {
#pragma unroll
        for (int rt = 0; rt < 4; ++rt) {
            float s = sq[rt];
            s += __shfl_xor(s, 16);
            s += __shfl_xor(s, 32);
            if (lg == 0) ENC2Wp[w * 64 + rt * 16 + lc] = s;
        }
    }
}

__global__ __launch_bounds__(256, 2) void vqvae_main_mfma(
    const float* __restrict__ action,
    const float* __restrict__ w1, const float* __restrict__ b1,
    const float* __restrict__ b2, const float* __restrict__ b3,
    const float* __restrict__ emb,
    const float* __restrict__ d1b, const float* __restrict__ d2b,
    const float* __restrict__ rb,
    float* __restrict__ out, float* __restrict__ ws)
{
    extern __shared__ __align__(16) unsigned short DYN[];
    unsigned short* HH = DYN;              // [64][264]
    unsigned short* HL = DYN + 64 * 264;   // [64][264]

    __shared__ float AT[64 * 6];
    __shared__ float E2S[512];
    __shared__ float TOPV[4][64][3];
    __shared__ float ENC2W[4 * 64];
    __shared__ int IDXR[64];
    __shared__ int FLAGR[64];
    __shared__ float RED[8];

    const int t = threadIdx.x;
    const int w = t >> 6, lane = t & 63;
    const int lc = lane & 15, lg = lane >> 4;
    const int row0 = blockIdx.x * 64;
    const unsigned short* wsb = (const unsigned short*)(ws + WS_SPLIT_F);
    const short8v* W2f = (const short8v*)wsb + OFF_W2 / 8;
    const short8v* W3f = (const short8v*)wsb + OFF_W3 / 8;
    const short8v* EMBf = (const short8v*)wsb + OFF_EMB / 8;
    const short8v* D1f = (const short8v*)wsb + OFF_D1 / 8;
    const short8v* D2f = (const short8v*)wsb + OFF_D2 / 8;
    const short8v* RWf = (const short8v*)wsb + OFF_RW / 8;

    // ---- stage action (row-major [r][6]) + e2 ----
    for (int i = t; i < 384; i += 256) AT[i] = action[(size_t)row0 * 6 + i];
    for (int i = t; i < 512; i += 256) E2S[i] = ws[WS_E2 + i];
    __syncthreads();

    // ---- enc1 (VALU fp32): h1[j=t][r=0..63] -> splits ----
    {
        float wr[6];
#pragma unroll
        for (int i = 0; i < 6; ++i) wr[i] = w1[t * 6 + i];
        float bb = b1[t];
        for (int r = 0; r < 64; ++r) {
            float s = bb;
#pragma unroll
            for (int i = 0; i < 6; ++i) s += wr[i] * AT[r * 6 + i];
            s = fmaxf(s, 0.f);
            unsigned short h, l;
            split2(s, h, l);
            HH[r * 264 + t] = h;
            HL[r * 264 + t] = l;
        }
    }

    // ---- enc2: 256 -> 256 relu ----
    mfma_mlp4<4, 8, true, false>(W2f, b2, HH, HL, ENC2W, w, lane);
    // ---- mu: 256 -> 128, no relu, + per-row ||enc||^2 partials ----
    mfma_mlp4<2, 8, false, true>(W3f, b3, HH, HL, ENC2W, w, lane);

    // ---- VQ: 2 passes x (4 kt x 4 c x 4 rt), running top-2 ----
    float lvq = 0.f, lrec = 0.f;
    {
        float v1[4][4], v2[4][4];
        int k1r[4][4];
#pragma unroll
        for (int rt = 0; rt < 4; ++rt)
#pragma unroll
            for (int reg = 0; reg < 4; ++reg) {
                v1[rt][reg] = 1e30f; v2[rt][reg] = 1e30f; k1r[rt][reg] = 0;
            }
        __syncthreads();  // enc splits ready
#pragma unroll
        for (int p = 0; p < 2; ++p) {
            f32x4 vacc[4][4];
#pragma unroll
            for (int kt = 0; kt < 4; ++kt)
#pragma unroll
                for (int rt = 0; rt < 4; ++rt)
                    vacc[kt][rt] = (f32x4){0.f, 0.f, 0.f, 0.f};
            for (int c = 0; c < 4; ++c) {
                const int aoff = c * 32 + lg * 8;
                short8v ah[4], al[4];
#pragma unroll
                for (int rt = 0; rt < 4; ++rt) {
                    ah[rt] = *(const short8v*)&HH[(rt * 16 + lc) * 264 + aoff];
                    al[rt] = *(const short8v*)&HL[(rt * 16 + lc) * 264 + aoff];
                }
#pragma unroll
                for (int kt = 0; kt < 4; ++kt) {
                    int ktg = w * 8 + p * 4 + kt;
                    int fi = ((ktg * 4 + c) * 2) * 64 + lane;
                    short8v bh = EMBf[fi];
                    short8v bl = EMBf[fi + 64];
#pragma unroll
                    for (int rt = 0; rt < 4; ++rt) {
                        vacc[kt][rt] = __builtin_amdgcn_mfma_f32_16x16x32_bf16(al[rt], bh, vacc[kt][rt], 0, 0, 0);
                        vacc[kt][rt] = __builtin_amdgcn_mfma_f32_16x16x32_bf16(ah[rt], bl, vacc[kt][rt], 0, 0, 0);
                        vacc[kt][rt] = __builtin_amdgcn_mfma_f32_16x16x32_bf16(ah[rt], bh, vacc[kt][rt], 0, 0, 0);
                    }
                }
            }
            // fold pass into running top-2 (ascending k)
#pragma unroll
            for (int kt = 0; kt < 4; ++kt) {
                int k = (w * 8 + p * 4 + kt) * 16 + lc;
                float ek = E2S[k];
#pragma unroll
                for (int rt = 0; rt < 4; ++rt)
#pragma unroll
                    for (int reg = 0; reg < 4; ++reg) {
                        float dd = ek - 2.f * vacc[kt][rt][reg];
                        if (dd < v1[rt][reg]) {
                            v2[rt][reg] = v1[rt][reg]; v1[rt][reg] = dd; k1r[rt][reg] = k;
                        } else if (dd < v2[rt][reg]) v2[rt][reg] = dd;
                    }
            }
        }
        __syncthreads();  // all VQ reads of HH/HL done

        // merge across the 16 lc lanes (xor<16 keeps lg)
#pragma unroll
        for (int m = 1; m < 16; m <<= 1) {
#pragma unroll
            for (int rt = 0; rt < 4; ++rt)
#pragma unroll
                for (int reg = 0; reg < 4; ++reg) {
                    float ov1 = __shfl_xor(v1[rt][reg], m);
                    int ok1 = __shfl_xor(k1r[rt][reg], m);
                    float ov2 = __shfl_xor(v2[rt][reg], m);
                    if (ov1 < v1[rt][reg] ||
                        (ov1 == v1[rt][reg] && ok1 < k1r[rt][reg])) {
                        v2[rt][reg] = fminf(v1[rt][reg], ov2);
                        v1[rt][reg] = ov1; k1r[rt][reg] = ok1;
                    } else {
                        v2[rt][reg] = fminf(v2[rt][reg], ov1);
                    }
                }
        }
        if (lc == 0) {
#pragma unroll
            for (int rt = 0; rt < 4; ++rt)
#pragma unroll
                for (int reg = 0; reg < 4; ++reg) {
                    int row = rt * 16 + lg * 4 + reg;
                    TOPV[w][row][0] = v1[rt][reg];
                    TOPV[w][row][1] = __int_as_float(k1r[rt][reg]);
                    TOPV[w][row][2] = v2[rt][reg];
                }
        }
    }
    __syncthreads();

    // ---- merge 4 wave candidates; idx out, flag, lvq = ||enc||^2 + dd_min ----
    if (t < 64) {
        float v1 = 1e30f, v2 = 1e30f; int k1 = 0;
#pragma unroll
        for (int ww = 0; ww < 4; ++ww) {
            float ov1 = TOPV[ww][t][0];
            int ok1 = __float_as_int(TOPV[ww][t][1]);
            float ov2 = TOPV[ww][t][2];
            if (ov1 < v1 || (ov1 == v1 && ok1 < k1)) {
                v2 = fminf(v1, ov2); v1 = ov1; k1 = ok1;
            } else {
                v2 = fminf(v2, ov1);
            }
        }
        int flag = (v2 - v1 >= MARGINF) ? 0 : 1;  // NaN-safe
        IDXR[t] = k1;
        FLAGR[t] = flag;
        int row = row0 + t;
        if (flag)
            atomicOr((unsigned int*)ws + WS_MASK + (row >> 5), 1u << (row & 31));
        out[row] = (float)k1;
        if (!flag) {
            float enc2 = ENC2W[0 * 64 + t] + ENC2W[1 * 64 + t] +
                         ENC2W[2 * 64 + t] + ENC2W[3 * 64 + t];
            lvq = enc2 + v1;
        }
    }
    __syncthreads();

    // ---- gather q (exact fp32), write q_st, split q -> HH/HL for decoder ----
    {
        int d = t & 127, rhalf = t >> 7;
#pragma unroll
        for (int e = 0; e < 32; ++e) {
            int r = (e << 1) | rhalf;
            int k1 = IDXR[r];
            float q = emb[(size_t)k1 * 128 + d];
            out[NB + (size_t)(row0 + r) * 128 + d] = q;
            unsigned short h, l;
            split2(q, h, l);
            HH[r * 264 + d] = h;
            HL[r * 264 + d] = l;
        }
    }

    // ---- decoder ----
    mfma_mlp4<4, 4, true, false>(D1f, d1b, HH, HL, ENC2W, w, lane);
    mfma_mlp4<4, 8, true, false>(D2f, d2b, HH, HL, ENC2W, w, lane);
    __syncthreads();  // dec2 splits ready

    // ---- rec: wave w handles rows w*16..+15 via MFMA ----
    {
        f32x4 racc = (f32x4){0.f, 0.f, 0.f, 0.f};
        for (int c = 0; c < 8; ++c) {
            const int boff = c * 32 + lg * 8;
            short8v bh = *(const short8v*)&HH[(w * 16 + lc) * 264 + boff];
            short8v bl = *(const short8v*)&HL[(w * 16 + lc) * 264 + boff];
            int fi = (c * 2) * 64 + lane;
            short8v ah = RWf[fi];
            short8v al = RWf[fi + 64];
            racc = __builtin_amdgcn_mfma_f32_16x16x32_bf16(al, bh, racc, 0, 0, 0);
            racc = __builtin_amdgcn_mfma_f32_16x16x32_bf16(ah, bl, racc, 0, 0, 0);
            racc = __builtin_amdgcn_mfma_f32_16x16x32_bf16(ah, bh, racc, 0, 0, 0);
        }
        int r = w * 16 + lc;
#pragma unroll
        for (int reg = 0; reg < 4; ++reg) {
            int j = lg * 4 + reg;
            if (j < 6) {
                float rec = tanhf(racc[reg] + rb[j]);
                float df = rec - AT[r * 6 + j];
                if (!FLAGR[r]) lrec += df * df;
            }
        }
    }

    // ---- block loss reduction -> hashed fp64 slots ----
#pragma unroll
    for (int m = 1; m < 64; m <<= 1) {
        lvq += __shfl_xor(lvq, m);
        lrec += __shfl_xor(lrec, m);
    }
    if ((t & 63) == 0) { RED[t >> 6] = lvq; RED[4 + (t >> 6)] = lrec; }
    __syncthreads();
    if (t == 0) {
        int slot = blockIdx.x & 63;
        atomicAdd((double*)ws + slot, (double)((RED[0] + RED[1]) + (RED[2] + RED[3])));
        atomicAdd((double*)ws + 64 + slot, (double)((RED[4] + RED[5]) + (RED[6] + RED[7])));
    }
}

// ---------------- fp64 repair of ambiguous rows ----------------
__global__ __launch_bounds__(256) void vqvae_fix(
    const float* __restrict__ action,
    const float* __restrict__ w1, const float* __restrict__ b1,
    const float* __restrict__ w2, const float* __restrict__ b2,
    const float* __restrict__ w3, const float* __restrict__ b3,
    const float* __restrict__ emb,
    const float* __restrict__ d1w, const float* __restrict__ d1b,
    const float* __restrict__ d2w, const float* __restrict__ d2b,
    const float* __restrict__ rw, const float* __restrict__ rb,
    float* __restrict__ out, float* __restrict__ ws)
{
    __shared__ double H1[256];
    __shared__ double H2[256];
    __shared__ double ENC[128];
    __shared__ double QD[128];
    __shared__ double SRED[256];
    __shared__ int SK[256];
    __shared__ double SA[6];

    const int t = threadIdx.x;
    const unsigned int word = ((const unsigned int*)ws)[WS_MASK + blockIdx.x];
    if (word == 0u) return;

    for (int bit = 0; bit < 32; ++bit) {
        if (!(word & (1u << bit))) continue;
        const int row = (blockIdx.x << 5) + bit;

        if (t < 6) SA[t] = (double)action[(size_t)row * 6 + t];
        __syncthreads();
        {
            double a = (double)b1[t];
#pragma unroll
            for (int i = 0; i < 6; ++i) a += (double)w1[t * 6 + i] * SA[i];
            H1[t] = a > 0.0 ? a : 0.0;
        }
        __syncthreads();
        {
            const float* w = w2 + (size_t)t * 256;
            double a0 = 0, a1 = 0, a2 = 0, a3 = 0;
            for (int i = 0; i < 256; i += 4) {
                a0 += (double)w[i] * H1[i];     a1 += (double)w[i + 1] * H1[i + 1];
                a2 += (double)w[i + 2] * H1[i + 2]; a3 += (double)w[i + 3] * H1[i + 3];
            }
            double a = (double)b2[t] + a0 + a1 + a2 + a3;
            H2[t] = a > 0.0 ? a : 0.0;
        }
        __syncthreads();
        if (t < 128) {
            const float* w = w3 + (size_t)t * 256;
            double a0 = 0, a1 = 0, a2 = 0, a3 = 0;
            for (int i = 0; i < 256; i += 4) {
                a0 += (double)w[i] * H2[i];     a1 += (double)w[i + 1] * H2[i + 1];
                a2 += (double)w[i + 2] * H2[i + 2]; a3 += (double)w[i + 3] * H2[i + 3];
            }
            ENC[t] = (double)b3[t] + a0 + a1 + a2 + a3;
        }
        __syncthreads();
        double best = 1e300; int bk = 0;
#pragma unroll
        for (int kk = 0; kk < 2; ++kk) {
            int k = t + kk * 256;
            const float* e = emb + (size_t)k * 128;
            double s0 = 0, s1 = 0;
            for (int d = 0; d < 128; d += 2) {
                double df0 = ENC[d] - (double)e[d];
                double df1 = ENC[d + 1] - (double)e[d + 1];
                s0 += df0 * df0; s1 += df1 * df1;
            }
            double s = s0 + s1;
            if (s < best) { best = s; bk = k; }
        }
        SRED[t] = best; SK[t] = bk;
        __syncthreads();
        for (int st = 128; st > 0; st >>= 1) {
            if (t < st) {
                double ov = SRED[t + st]; int ok = SK[t + st];
                if (ov < SRED[t] || (ov == SRED[t] && ok < SK[t])) { SRED[t] = ov; SK[t] = ok; }
            }
            __syncthreads();
        }
        const int bestk = SK[0];
        double lv = 0.0;
        if (t < 128) {
            double q = (double)emb[(size_t)bestk * 128 + t];
            QD[t] = q;
            double df = ENC[t] - q;
            lv = df * df;
            out[NB + (size_t)row * 128 + t] = (float)q;
        }
        if (t == 0) out[row] = (float)bestk;
        __syncthreads();
        {
            const float* w = d1w + (size_t)t * 128;
            double a0 = 0, a1 = 0;
            for (int i = 0; i < 128; i += 2) {
                a0 += (double)w[i] * QD[i]; a1 += (double)w[i + 1] * QD[i + 1];
            }
            double a = (double)d1b[t] + a0 + a1;
            H1[t] = a > 0.0 ? a : 0.0;
        }
        __syncthreads();
        {
            const float* w = d2w + (size_t)t * 256;
            double a0 = 0, a1 = 0, a2 = 0, a3 = 0;
            for (int i = 0; i < 256; i += 4) {
                a0 += (double)w[i] * H1[i];     a1 += (double)w[i + 1] * H1[i + 1];
                a2 += (double)w[i + 2] * H1[i + 2]; a3 += (double)w[i + 3] * H1[i + 3];
            }
            double a = (double)d2b[t] + a0 + a1 + a2 + a3;
            H2[t] = a > 0.0 ? a : 0.0;
        }
        __syncthreads();
        double lr = 0.0;
        if (t < 6) {
            const float* w = rw + (size_t)t * 256;
            double a0 = 0, a1 = 0;
            for (int i = 0; i < 256; i += 2) {
                a0 += (double)w[i] * H2[i]; a1 += (double)w[i + 1] * H2[i + 1];
            }
            double rec = tanh((double)rb[t] + a0 + a1);
            double df = rec - SA[t];
            lr = df * df;
        }
        SRED[t] = lv;
        __syncthreads();
        for (int st = 128; st > 0; st >>= 1) {
            if (t < st) SRED[t] += SRED[t + st];
            __syncthreads();
        }
        if (t == 0) atomicAdd((double*)ws + 0, SRED[0]);
        if (t < 6) atomicAdd((double*)ws + 64, lr);
        __syncthreads();
    }
}

__global__ void vqvae_fin(const float* __restrict__ ws, float* __restrict__ out) {
    if (threadIdx.x == 0 && blockIdx.x == 0) {
        const double* D = (const double*)ws;
        double sv = 0.0, sr = 0.0;
        for (int i = 0; i < 64; ++i) { sv += D[i]; sr += D[64 + i]; }
        double loss = sr / ((double)NB * 6.0) + 1.25 * (sv / ((double)NB * 128.0));
        out[(size_t)NB * 129] = (float)loss;
    }
}

// ---------------- fp32 fallback (round-4 structure; rarely used) ----------------
static __device__ __forceinline__ void gemm_out256(
    const float* __restrict__ W, const float* __restrict__ bias, int IN,
    const float* __restrict__ hin, float* __restrict__ hout,
    float* __restrict__ WC, int t, int tx, int r0, bool do_relu)
{
    float acc[2][4][4];
#pragma unroll
    for (int g = 0; g < 2; ++g)
#pragma unroll
        for (int a = 0; a < 4; ++a)
#pragma unroll
            for (int b = 0; b < 4; ++b) acc[g][a][b] = 0.f;
    float4 pa = *(const float4*)(W + (size_t)t * IN);
    float4 pb = *(const float4*)(W + (size_t)t * IN + 4);
    for (int i0 = 0; i0 < IN; i0 += 8) {
        __syncthreads();
        WC[0 * 256 + t] = pa.x; WC[1 * 256 + t] = pa.y;
        WC[2 * 256 + t] = pa.z; WC[3 * 256 + t] = pa.w;
        WC[4 * 256 + t] = pb.x; WC[5 * 256 + t] = pb.y;
        WC[6 * 256 + t] = pb.z; WC[7 * 256 + t] = pb.w;
        __syncthreads();
        if (i0 + 8 < IN) {
            pa = *(const float4*)(W + (size_t)t * IN + i0 + 8);
            pb = *(const float4*)(W + (size_t)t * IN + i0 + 12);
        }
#pragma unroll
        for (int i = 0; i < 8; ++i) {
            int row = i0 + i;
            float4 h = *(const float4*)&hin[row * 32 + (r0 ^ SWC(row))];
            float4 w0 = *(const float4*)&WC[i * 256 + 4 * tx];
            float4 w1v = *(const float4*)&WC[i * 256 + 128 + 4 * tx];
            float wv0[4] = {w0.x, w0.y, w0.z, w0.w};
            float wv1[4] = {w1v.x, w1v.y, w1v.z, w1v.w};
            float hv[4] = {h.x, h.y, h.z, h.w};
#pragma unroll
            for (int a = 0; a < 4; ++a)
#pragma unroll
                for (int b = 0; b < 4; ++b) {
                    acc[0][a][b] += wv0[a] * hv[b];
                    acc[1][a][b] += wv1[a] * hv[b];
                }
        }
    }
#pragma unroll
    for (int g = 0; g < 2; ++g)
#pragma unroll
        for (int a = 0; a < 4; ++a) {
            int j = g * 128 + 4 * tx + a;
            float bj = bias[j];
            float4 v;
            v.x = acc[g][a][0] + bj; v.y = acc[g][a][1] + bj;
            v.z = acc[g][a][2] + bj; v.w = acc[g][a][3] + bj;
            if (do_relu) {
                v.x = fmaxf(v.x, 0.f); v.y = fmaxf(v.y, 0.f);
                v.z = fmaxf(v.z, 0.f); v.w = fmaxf(v.w, 0.f);
            }
            *(float4*)&hout[j * 32 + (r0 ^ SWC(j))] = v;
        }
    __syncthreads();
}

__global__ __launch_bounds__(256, 2) void vqvae_main_fp32(
    const float* __restrict__ action,
    const float* __restrict__ w1, const float* __restrict__ b1,
    const float* __restrict__ w2, const float* __restrict__ b2,
    const float* __restrict__ w3, const float* __restrict__ b3,
    const float* __restrict__ emb,
    const float* __restrict__ d1w, const float* __restrict__ d1b,
    const float* __restrict__ d2w, const float* __restrict__ d2b,
    const float* __restrict__ rw, const float* __restrict__ rb,
    float* __restrict__ out, float* __restrict__ ws)
{
    __shared__ float X[256 * 32];
    __shared__ float Y[256 * 32];
    __shared__ float WC[2048];
    __shared__ float AT[6 * 32];
    __shared__ int IDXR[32];
    __shared__ int FLAGR[32];
    __shared__ float RED[8];

    const int t = threadIdx.x;
    const int tx = t & 31, ty = t >> 5;
    const int r0 = ty * 4;
    const int row0 = blockIdx.x * 32;

    if (t < 192) {
        int r = t / 6, i = t - r * 6;
        AT[i * 32 + r] = action[(size_t)row0 * 6 + t];
    }
    __syncthreads();
    {
#pragma unroll
        for (int i = 0; i < 6; ++i) WC[i * 256 + t] = w1[t * 6 + i];
        __syncthreads();
        float acc[2][4][4];
#pragma unroll
        for (int g = 0; g < 2; ++g)
#pragma unroll
            for (int a = 0; a < 4; ++a)
#pragma unroll
                for (int b = 0; b < 4; ++b) acc[g][a][b] = 0.f;
#pragma unroll
        for (int i = 0; i < 6; ++i) {
            float4 h = *(const float4*)&AT[i * 32 + r0];
            float4 w0 = *(const float4*)&WC[i * 256 + 4 * tx];
            float4 w1v = *(const float4*)&WC[i * 256 + 128 + 4 * tx];
            float wv0[4] = {w0.x, w0.y, w0.z, w0.w};
            float wv1[4] = {w1v.x, w1v.y, w1v.z, w1v.w};
            float hv[4] = {h.x, h.y, h.z, h.w};
#pragma unroll
            for (int a = 0; a < 4; ++a)
#pragma unroll
                for (int b = 0; b < 4; ++b) {
                    acc[0][a][b] += wv0[a] * hv[b];
                    acc[1][a][b] += wv1[a] * hv[b];
                }
        }
#pragma unroll
        for (int g = 0; g < 2; ++g)
#pragma unroll
            for (int a = 0; a < 4; ++a) {
                int j = g * 128 + 4 * tx + a;
                float bj = b1[j];
                float4 v;
                v.x = fmaxf(acc[g][a][0] + bj, 0.f);
                v.y = fmaxf(acc[g][a][1] + bj, 0.f);
                v.z = fmaxf(acc[g][a][2] + bj, 0.f);
                v.w = fmaxf(acc[g][a][3] + bj, 0.f);
                *(float4*)&X[j * 32 + (r0 ^ SWC(j))] = v;
            }
        __syncthreads();
    }
    gemm_out256(w2, b2, 256, X, Y, WC, t, tx, r0, true);
    {
        float acc[4][4];
#pragma unroll
        for (int a = 0; a < 4; ++a)
#pragma unroll
            for (int b = 0; b < 4; ++b) acc[a][b] = 0.f;
        float4 pa, pb;
        if (t < 128) {
            pa = *(const float4*)(w3 + (size_t)t * 256);
            pb = *(const float4*)(w3 + (size_t)t * 256 + 4);
        }
        for (int i0 = 0; i0 < 256; i0 += 8) {
            __syncthreads();
            if (t < 128) {
                WC[0 * 128 + t] = pa.x; WC[1 * 128 + t] = pa.y;
                WC[2 * 128 + t] = pa.z; WC[3 * 128 + t] = pa.w;
                WC[4 * 128 + t] = pb.x; WC[5 * 128 + t] = pb.y;
                WC[6 * 128 + t] = pb.z; WC[7 * 128 + t] = pb.w;
            }
            __syncthreads();
            if (t < 128 && i0 + 8 < 256) {
                pa = *(const float4*)(w3 + (size_t)t * 256 + i0 + 8);
                pb = *(const float4*)(w3 + (size_t)t * 256 + i0 + 12);
            }
#pragma unroll
            for (int i = 0; i < 8; ++i) {
                int row = i0 + i;
                float4 h = *(const float4*)&Y[row * 32 + (r0 ^ SWC(row))];
                float4 w0 = *(const float4*)&WC[i * 128 + 4 * tx];
                float wv[4] = {w0.x, w0.y, w0.z, w0.w};
                float hv[4] = {h.x, h.y, h.z, h.w};
#pragma unroll
                for (int a = 0; a < 4; ++a)
#pragma unroll
                    for (int b = 0; b < 4; ++b) acc[a][b] += wv[a] * hv[b];
            }
        }
#pragma unroll
        for (int a = 0; a < 4; ++a) {
            int j = 4 * tx + a;
            float bj = b3[j];
            float4 v;
            v.x = acc[a][0] + bj; v.y = acc[a][1] + bj;
            v.z = acc[a][2] + bj; v.w = acc[a][3] + bj;
            *(float4*)&X[j * 32 + (r0 ^ SWC(j))] = v;
        }
        __syncthreads();
    }
    {
        float bv1[4], bv2[4];
        int bk1[4];
        float acc[4][4][4];
#pragma unroll
        for (int p = 0; p < 4; ++p)
#pragma unroll
            for (int a = 0; a < 4; ++a)
#pragma unroll
                for (int b = 0; b < 4; ++b) acc[p][a][b] = 0.f;
        float4 qa = *(const float4*)(emb + (size_t)t * 128);
        float4 qb = *(const float4*)(emb + (size_t)(t + 256) * 128);
        for (int d0 = 0; d0 < 128; d0 += 4) {
            __syncthreads();
            WC[0 * 512 + t] = qa.x; WC[1 * 512 + t] = qa.y;
            WC[2 * 512 + t] = qa.z; WC[3 * 512 + t] = qa.w;
            WC[0 * 512 + 256 + t] = qb.x; WC[1 * 512 + 256 + t] = qb.y;
            WC[2 * 512 + 256 + t] = qb.z; WC[3 * 512 + 256 + t] = qb.w;
            __syncthreads();
            if (d0 + 4 < 128) {
                qa = *(const float4*)(emb + (size_t)t * 128 + d0 + 4);
                qb = *(const float4*)(emb + (size_t)(t + 256) * 128 + d0 + 4);
            }
#pragma unroll
            for (int i = 0; i < 4; ++i) {
                int row = d0 + i;
                float4 h = *(const float4*)&X[row * 32 + (r0 ^ SWC(row))];
                float hv[4] = {h.x, h.y, h.z, h.w};
#pragma unroll
                for (int p = 0; p < 4; ++p) {
                    float4 w0 = *(const float4*)&WC[i * 512 + p * 128 + 4 * tx];
                    float wv[4] = {w0.x, w0.y, w0.z, w0.w};
#pragma unroll
                    for (int a = 0; a < 4; ++a)
#pragma unroll
                        for (int b = 0; b < 4; ++b) acc[p][a][b] += wv[a] * hv[b];
                }
            }
        }
#pragma unroll
        for (int b = 0; b < 4; ++b) { bv1[b] = 1e30f; bv2[b] = 1e30f; bk1[b] = 0; }
#pragma unroll
        for (int p = 0; p < 4; ++p)
#pragma unroll
            for (int a = 0; a < 4; ++a) {
                int k = p * 128 + 4 * tx + a;
                float ek = ws[WS_E2 + k];
#pragma unroll
                for (int b = 0; b < 4; ++b) {
                    float dd = ek - 2.f * acc[p][a][b];
                    if (dd < bv1[b]) { bv2[b] = bv1[b]; bv1[b] = dd; bk1[b] = k; }
                    else if (dd < bv2[b]) bv2[b] = dd;
                }
            }
#pragma unroll
        for (int m = 1; m < 32; m <<= 1) {
#pragma unroll
            for (int b = 0; b < 4; ++b) {
                float ov1 = __shfl_xor(bv1[b], m);
                int ok1 = __shfl_xor(bk1[b], m);
                float ov2 = __shfl_xor(bv2[b], m);
                if (ov1 < bv1[b] || (ov1 == bv1[b] && ok1 < bk1[b])) {
                    bv2[b] = fminf(bv1[b], ov2);
                    bv1[b] = ov1; bk1[b] = ok1;
                } else {
                    bv2[b] = fminf(bv2[b], ov1);
                }
            }
        }
        if (tx == 0) {
#pragma unroll
            for (int b = 0; b < 4; ++b) {
                IDXR[r0 + b] = bk1[b];
                FLAGR[r0 + b] = (bv2[b] - bv1[b] >= MARGINF) ? 0 : 1;
            }
        }
    }
    __syncthreads();
    if (t < 32) {
        int row = row0 + t;
        if (FLAGR[t])
            atomicOr((unsigned int*)ws + WS_MASK + (row >> 5), 1u << (row & 31));
        out[row] = (float)IDXR[t];
    }
    float lvq = 0.f, lrec = 0.f;
    {
        int d = t & 127, rq = t >> 7;
        int cd = SWC(d);
#pragma unroll
        for (int e = 0; e < 4; ++e) {
            int rr = (rq + 2 * e) * 4;
            float4 en = *(const float4*)&X[d * 32 + (rr ^ cd)];
            float q0 = emb[(size_t)IDXR[rr + 0] * 128 + d];
            float q1 = emb[(size_t)IDXR[rr + 1] * 128 + d];
            float q2 = emb[(size_t)IDXR[rr + 2] * 128 + d];
            float q3 = emb[(size_t)IDXR[rr + 3] * 128 + d];
            float4 qv; qv.x = q0; qv.y = q1; qv.z = q2; qv.w = q3;
            *(float4*)&X[(128 + d) * 32 + (rr ^ cd)] = qv;
            if (!FLAGR[rr + 0]) lvq += (en.x - q0) * (en.x - q0);
            if (!FLAGR[rr + 1]) lvq += (en.y - q1) * (en.y - q1);
            if (!FLAGR[rr + 2]) lvq += (en.z - q2) * (en.z - q2);
            if (!FLAGR[rr + 3]) lvq += (en.w - q3) * (en.w - q3);
            out[NB + (size_t)(row0 + rr + 0) * 128 + d] = q0;
            out[NB + (size_t)(row0 + rr + 1) * 128 + d] = q1;
            out[NB + (size_t)(row0 + rr + 2) * 128 + d] = q2;
            out[NB + (size_t)(row0 + rr + 3) * 128 + d] = q3;
        }
    }
    __syncthreads();
    gemm_out256(d1w, d1b, 128, X + 128 * 32, Y, WC, t, tx, r0, true);
    gemm_out256(d2w, d2b, 256, Y, X, WC, t, tx, r0, true);
    if (t < 192) {
        int jj = t >> 5, r = t & 31;
        const float* wr = rw + jj * 256;
        float a0 = 0.f, a1 = 0.f, a2 = 0.f, a3 = 0.f;
        for (int i = 0; i < 256; i += 4) {
            a0 += wr[i] * X[i * 32 + (r ^ SWC(i))];
            a1 += wr[i + 1] * X[(i + 1) * 32 + (r ^ SWC(i + 1))];
            a2 += wr[i + 2] * X[(i + 2) * 32 + (r ^ SWC(i + 2))];
            a3 += wr[i + 3] * X[(i + 3) * 32 + (r ^ SWC(i + 3))];
        }
        float rec = tanhf(rb[jj] + (a0 + a1) + (a2 + a3));
        float df = rec - AT[jj * 32 + r];
        if (!FLAGR[r]) lrec = df * df;
    }
#pragma unroll
    for (int m = 1; m < 64; m <<= 1) {
        lvq += __shfl_xor(lvq, m);
        lrec += __shfl_xor(lrec, m);
    }
    if ((t & 63) == 0) { RED[t >> 6] = lvq; RED[4 + (t >> 6)] = lrec; }
    __syncthreads();
    if (t == 0) {
        int slot = blockIdx.x & 63;
        atomicAdd((double*)ws + slot, (double)((RED[0] + RED[1]) + (RED[2] + RED[3])));
        atomicAdd((double*)ws + 64 + slot, (double)((RED[4] + RED[5]) + (RED[6] + RED[7])));
    }
}

extern "C" void kernel_launch(void* const* d_in, const int* in_sizes, int n_in,
                              void* d_out, int out_size, void* d_ws, size_t ws_size,
                              hipStream_t stream) {
    const float* action = (const float*)d_in[0];
    const float* w1 = (const float*)d_in[1];
    const float* b1 = (const float*)d_in[2];
    const float* w2 = (const float*)d_in[3];
    const float* b2 = (const float*)d_in[4];
    const float* w3 = (const float*)d_in[5];
    const float* b3 = (const float*)d_in[6];
    const float* emb = (const float*)d_in[7];
    const float* d1w = (const float*)d_in[8];
    const float* d1b = (const float*)d_in[9];
    const float* d2w = (const float*)d_in[10];
    const float* d2b = (const float*)d_in[11];
    const float* rw = (const float*)d_in[12];
    const float* rb = (const float*)d_in[13];
    float* out = (float*)d_out;
    float* ws = (float*)d_ws;

    const size_t need_mfma = (size_t)WS_BASE_BYTES + (size_t)SPLIT_TOTAL * 2;
    const int use_mfma = (ws_size >= need_mfma) ? 1 : 0;
    const int dyn_lds = 64 * 264 * 2 * 2;  // 67584 B

    size_t clear = ws_size < (size_t)WS_BASE_BYTES ? ws_size : (size_t)WS_BASE_BYTES;
    hipMemsetAsync(d_ws, 0, clear, stream);

    prep_kernel<<<1043, 256, 0, stream>>>(w2, w3, emb, d1w, d2w, rw, ws, use_mfma);
    if (use_mfma) {
        hipFuncSetAttribute((const void*)vqvae_main_mfma,
                            hipFuncAttributeMaxDynamicSharedMemorySize, dyn_lds);
        vqvae_main_mfma<<<NB / 64, 256, dyn_lds, stream>>>(action, w1, b1, b2, b3, emb,
                                                           d1b, d2b, rb, out, ws);
    } else {
        vqvae_main_fp32<<<NB / 32, 256, 0, stream>>>(action, w1, b1, w2, b2, w3, b3, emb,
                                                     d1w, d1b, d2w, d2b, rw, rb, out, ws);
    }
    vqvae_fix<<<NB / 32, 256, 0, stream>>>(action, w1, b1, w2, b2, w3, b3, emb,
                                           d1w, d1b, d2w, d2b, rw, rb, out, ws);
    vqvae_fin<<<1, 64, 0, stream>>>(ws, out);
}

// Round 7
// 395.622 us; speedup vs baseline: 3.6174x; 1.2140x over previous
//
#include <hip/hip_runtime.h>
#include <hip/hip_bf16.h>

#define NB 131072
#define MARGINF 5e-7f
// ws layout: doubles[128] at float idx 0..255 (vq slots 0..63, rec slots 64..127);
// e2[512] at float idx 256..767; bitmask u32[4096] at word idx 768..4863;
// bf16 split-weight region from float idx 4864.
#define WS_E2 256
#define WS_MASK 768
#define WS_MASKW 4096
#define WS_BASE_BYTES ((768 + 4096) * 4)
#define WS_SPLIT_F 4864
// split region offsets (bf16 element units, relative to split base)
#define OFF_W2 0
#define OFF_W3 131072
#define OFF_EMB 196608
#define OFF_D1 327680
#define OFF_D2 393216
#define OFF_RW 524288
#define SPLIT_TOTAL 532480

typedef __attribute__((ext_vector_type(8))) short short8v;
typedef __attribute__((ext_vector_type(4))) float f32x4;
typedef __attribute__((ext_vector_type(4))) unsigned short ushort4v;

#define SWC(j) ((((j) >> 2) & 7) << 2)

__device__ __forceinline__ unsigned short bf16rn(float x) {
    unsigned u = __float_as_uint(x);
    unsigned r = u + 0x7fffu + ((u >> 16) & 1u);
    return (unsigned short)(r >> 16);
}
__device__ __forceinline__ void split2(float x, unsigned short& h, unsigned short& l) {
    h = bf16rn(x);
    float hf = __uint_as_float((unsigned)h << 16);
    l = bf16rn(x - hf);
}

// ---------------- prep: e2 + fragment-linear bf16 weight splits ----------------
__global__ void prep_kernel(
    const float* __restrict__ w2, const float* __restrict__ w3,
    const float* __restrict__ emb, const float* __restrict__ d1w,
    const float* __restrict__ d2w, const float* __restrict__ rw,
    float* __restrict__ ws, int do_splits)
{
    const int total = 512 + 266240;
    unsigned short* wsb = (unsigned short*)(ws + WS_SPLIT_F);
    for (int idx = blockIdx.x * 256 + threadIdx.x; idx < total; idx += gridDim.x * 256) {
        if (idx < 512) {
            const float* e = emb + (size_t)idx * 128;
            float s0 = 0.f, s1 = 0.f, s2 = 0.f, s3 = 0.f;
            for (int d = 0; d < 128; d += 4) {
                s0 += e[d] * e[d];     s1 += e[d + 1] * e[d + 1];
                s2 += e[d + 2] * e[d + 2]; s3 += e[d + 3] * e[d + 3];
            }
            ws[WS_E2 + idx] = (s0 + s1) + (s2 + s3);
            continue;
        }
        if (!do_splits) continue;
        int j = idx - 512;
        int base, K, o, k;
        float src;
        if (j < 65536) {            // w2: 256x256
            o = j >> 8; k = j & 255; base = OFF_W2; K = 256; src = w2[o * 256 + k];
        } else if (j < 98304) {     // w3: 128x256
            j -= 65536; o = j >> 8; k = j & 255; base = OFF_W3; K = 256; src = w3[o * 256 + k];
        } else if (j < 163840) {    // emb: 512x128
            j -= 98304; o = j >> 7; k = j & 127; base = OFF_EMB; K = 128; src = emb[o * 128 + k];
        } else if (j < 196608) {    // d1w: 256x128
            j -= 163840; o = j >> 7; k = j & 127; base = OFF_D1; K = 128; src = d1w[o * 128 + k];
        } else if (j < 262144) {    // d2w: 256x256
            j -= 196608; o = j >> 8; k = j & 255; base = OFF_D2; K = 256; src = d2w[o * 256 + k];
        } else {                    // rw padded to 16 rows: 16x256
            j -= 262144; o = j >> 8; k = j & 255; base = OFF_RW; K = 256;
            src = (o < 6) ? rw[o * 256 + k] : 0.f;
        }
        unsigned short h, l;
        split2(src, h, l);
        int jt = o >> 4, c = k >> 5;
        int lane = (((k >> 3) & 3) << 4) | (o & 15);
        int e = k & 7;
        int a = base + ((jt * (K >> 5) + c) * 2) * 512 + lane * 8 + e;
        wsb[a] = h;
        wsb[a + 512] = l;
    }
}

// ---------------- MFMA main kernel: 64 rows/block, 4 waves ----------------
// Activations hi/lo bf16 in dynamic LDS [64 rows][264]. Weight frags from ws (L2).
// TERMS=3: error-compensated (encoder/VQ path). TERMS=1: hi-only (decoder path).
// WRITELO: store lo split of output (needed only if consumer is TERMS=3).

template<int NJT, int KC, bool RELU, bool SQSUM, int TERMS, bool WRITELO>
__device__ __forceinline__ void mfma_mlp4(
    const short8v* __restrict__ Wf, const float* __restrict__ bias,
    unsigned short* HHp, unsigned short* HLp, float* ENC2Wp,
    int w, int lane)
{
    const int lc = lane & 15, lg = lane >> 4;
    f32x4 acc[NJT][4];
#pragma unroll
    for (int jj = 0; jj < NJT; ++jj)
#pragma unroll
        for (int rt = 0; rt < 4; ++rt)
            acc[jj][rt] = (f32x4){0.f, 0.f, 0.f, 0.f};

    __syncthreads();  // inputs ready
    for (int c = 0; c < KC; ++c) {
        const int boff = c * 32 + lg * 8;
        short8v bh[4], bl[4];
#pragma unroll
        for (int rt = 0; rt < 4; ++rt) {
            bh[rt] = *(const short8v*)&HHp[(rt * 16 + lc) * 264 + boff];
            if (TERMS == 3)
                bl[rt] = *(const short8v*)&HLp[(rt * 16 + lc) * 264 + boff];
        }
#pragma unroll
        for (int jj = 0; jj < NJT; ++jj) {
            int fi = (((w * NJT + jj) * KC + c) * 2) * 64 + lane;
            short8v ah = Wf[fi];
            if (TERMS == 3) {
                short8v al = Wf[fi + 64];
#pragma unroll
                for (int rt = 0; rt < 4; ++rt) {
                    acc[jj][rt] = __builtin_amdgcn_mfma_f32_16x16x32_bf16(al, bh[rt], acc[jj][rt], 0, 0, 0);
                    acc[jj][rt] = __builtin_amdgcn_mfma_f32_16x16x32_bf16(ah, bl[rt], acc[jj][rt], 0, 0, 0);
                    acc[jj][rt] = __builtin_amdgcn_mfma_f32_16x16x32_bf16(ah, bh[rt], acc[jj][rt], 0, 0, 0);
                }
            } else {
#pragma unroll
                for (int rt = 0; rt < 4; ++rt)
                    acc[jj][rt] = __builtin_amdgcn_mfma_f32_16x16x32_bf16(ah, bh[rt], acc[jj][rt], 0, 0, 0);
            }
        }
    }
    __syncthreads();  // all reads done; in-place writes now safe

    float sq[4] = {0.f, 0.f, 0.f, 0.f};
#pragma unroll
    for (int jj = 0; jj < NJT; ++jj) {
        int j0 = (w * NJT + jj) * 16 + lg * 4;
        float4 bv = *(const float4*)&bias[j0];
        float bb[4] = {bv.x, bv.y, bv.z, bv.w};
#pragma unroll
        for (int rt = 0; rt < 4; ++rt) {
            int r = rt * 16 + lc;
            ushort4v hv, lv;
#pragma unroll
            for (int reg = 0; reg < 4; ++reg) {
                float v = acc[jj][rt][reg] + bb[reg];
                if (RELU) v = fmaxf(v, 0.f);
                if (SQSUM) sq[rt] += v * v;
                if (WRITELO) {
                    unsigned short h, l;
                    split2(v, h, l);
                    hv[reg] = h; lv[reg] = l;
                } else {
                    hv[reg] = bf16rn(v);
                }
            }
            *(ushort4v*)&HHp[r * 264 + j0] = hv;
            if (WRITELO) *(ushort4v*)&HLp[r * 264 + j0] = lv;
        }
    }
    if (SQSUM) {
#pragma unroll
        for (int rt = 0; rt < 4; ++rt) {
            float s = sq[rt];
            s += __shfl_xor(s, 16);
            s += __shfl_xor(s, 32);
            if (lg == 0) ENC2Wp[w * 64 + rt * 16 + lc] = s;
        }
    }
}

__global__ __launch_bounds__(256, 2) void vqvae_main_mfma(
    const float* __restrict__ action,
    const float* __restrict__ w1, const float* __restrict__ b1,
    const float* __restrict__ b2, const float* __restrict__ b3,
    const float* __restrict__ emb,
    const float* __restrict__ d1b, const float* __restrict__ d2b,
    const float* __restrict__ rb,
    float* __restrict__ out, float* __restrict__ ws)
{
    extern __shared__ __align__(16) unsigned short DYN[];
    unsigned short* HH = DYN;              // [64][264]
    unsigned short* HL = DYN + 64 * 264;   // [64][264]

    __shared__ float AT[64 * 6];
    __shared__ float E2S[512];
    __shared__ float TOPV[4][64][3];
    __shared__ float ENC2W[4 * 64];
    __shared__ int IDXR[64];
    __shared__ int FLAGR[64];
    __shared__ float RED[8];

    const int t = threadIdx.x;
    const int w = t >> 6, lane = t & 63;
    const int lc = lane & 15, lg = lane >> 4;
    const int row0 = blockIdx.x * 64;
    const unsigned short* wsb = (const unsigned short*)(ws + WS_SPLIT_F);
    const short8v* W2f = (const short8v*)wsb + OFF_W2 / 8;
    const short8v* W3f = (const short8v*)wsb + OFF_W3 / 8;
    const short8v* EMBf = (const short8v*)wsb + OFF_EMB / 8;
    const short8v* D1f = (const short8v*)wsb + OFF_D1 / 8;
    const short8v* D2f = (const short8v*)wsb + OFF_D2 / 8;
    const short8v* RWf = (const short8v*)wsb + OFF_RW / 8;

    // ---- stage action (row-major [r][6]) + e2 ----
    for (int i = t; i < 384; i += 256) AT[i] = action[(size_t)row0 * 6 + i];
    for (int i = t; i < 512; i += 256) E2S[i] = ws[WS_E2 + i];
    __syncthreads();

    // ---- enc1 (VALU fp32): h1[j=t][r=0..63] -> splits ----
    {
        float wr[6];
#pragma unroll
        for (int i = 0; i < 6; ++i) wr[i] = w1[t * 6 + i];
        float bb = b1[t];
        for (int r = 0; r < 64; ++r) {
            float s = bb;
#pragma unroll
            for (int i = 0; i < 6; ++i) s += wr[i] * AT[r * 6 + i];
            s = fmaxf(s, 0.f);
            unsigned short h, l;
            split2(s, h, l);
            HH[r * 264 + t] = h;
            HL[r * 264 + t] = l;
        }
    }

    // ---- enc2: 256 -> 256 relu (3-term, hi/lo out) ----
    mfma_mlp4<4, 8, true, false, 3, true>(W2f, b2, HH, HL, ENC2W, w, lane);
    // ---- mu: 256 -> 128, no relu, + per-row ||enc||^2 partials (3-term, hi/lo out) ----
    mfma_mlp4<2, 8, false, true, 3, true>(W3f, b3, HH, HL, ENC2W, w, lane);

    // ---- VQ: 2 passes x (4 kt x 4 c x 4 rt), running top-2 (3-term) ----
    float lvq = 0.f, lrec = 0.f;
    {
        float v1[4][4], v2[4][4];
        int k1r[4][4];
#pragma unroll
        for (int rt = 0; rt < 4; ++rt)
#pragma unroll
            for (int reg = 0; reg < 4; ++reg) {
                v1[rt][reg] = 1e30f; v2[rt][reg] = 1e30f; k1r[rt][reg] = 0;
            }
        __syncthreads();  // enc splits ready
#pragma unroll
        for (int p = 0; p < 2; ++p) {
            f32x4 vacc[4][4];
#pragma unroll
            for (int kt = 0; kt < 4; ++kt)
#pragma unroll
                for (int rt = 0; rt < 4; ++rt)
                    vacc[kt][rt] = (f32x4){0.f, 0.f, 0.f, 0.f};
            for (int c = 0; c < 4; ++c) {
                const int aoff = c * 32 + lg * 8;
                short8v ah[4], al[4];
#pragma unroll
                for (int rt = 0; rt < 4; ++rt) {
                    ah[rt] = *(const short8v*)&HH[(rt * 16 + lc) * 264 + aoff];
                    al[rt] = *(const short8v*)&HL[(rt * 16 + lc) * 264 + aoff];
                }
#pragma unroll
                for (int kt = 0; kt < 4; ++kt) {
                    int ktg = w * 8 + p * 4 + kt;
                    int fi = ((ktg * 4 + c) * 2) * 64 + lane;
                    short8v bh = EMBf[fi];
                    short8v bl = EMBf[fi + 64];
#pragma unroll
                    for (int rt = 0; rt < 4; ++rt) {
                        vacc[kt][rt] = __builtin_amdgcn_mfma_f32_16x16x32_bf16(al[rt], bh, vacc[kt][rt], 0, 0, 0);
                        vacc[kt][rt] = __builtin_amdgcn_mfma_f32_16x16x32_bf16(ah[rt], bl, vacc[kt][rt], 0, 0, 0);
                        vacc[kt][rt] = __builtin_amdgcn_mfma_f32_16x16x32_bf16(ah[rt], bh, vacc[kt][rt], 0, 0, 0);
                    }
                }
            }
            // fold pass into running top-2 (ascending k)
#pragma unroll
            for (int kt = 0; kt < 4; ++kt) {
                int k = (w * 8 + p * 4 + kt) * 16 + lc;
                float ek = E2S[k];
#pragma unroll
                for (int rt = 0; rt < 4; ++rt)
#pragma unroll
                    for (int reg = 0; reg < 4; ++reg) {
                        float dd = ek - 2.f * vacc[kt][rt][reg];
                        if (dd < v1[rt][reg]) {
                            v2[rt][reg] = v1[rt][reg]; v1[rt][reg] = dd; k1r[rt][reg] = k;
                        } else if (dd < v2[rt][reg]) v2[rt][reg] = dd;
                    }
            }
        }
        __syncthreads();  // all VQ reads of HH/HL done

        // merge across the 16 lc lanes (xor<16 keeps lg)
#pragma unroll
        for (int m = 1; m < 16; m <<= 1) {
#pragma unroll
            for (int rt = 0; rt < 4; ++rt)
#pragma unroll
                for (int reg = 0; reg < 4; ++reg) {
                    float ov1 = __shfl_xor(v1[rt][reg], m);
                    int ok1 = __shfl_xor(k1r[rt][reg], m);
                    float ov2 = __shfl_xor(v2[rt][reg], m);
                    if (ov1 < v1[rt][reg] ||
                        (ov1 == v1[rt][reg] && ok1 < k1r[rt][reg])) {
                        v2[rt][reg] = fminf(v1[rt][reg], ov2);
                        v1[rt][reg] = ov1; k1r[rt][reg] = ok1;
                    } else {
                        v2[rt][reg] = fminf(v2[rt][reg], ov1);
                    }
                }
        }
        if (lc == 0) {
#pragma unroll
            for (int rt = 0; rt < 4; ++rt)
#pragma unroll
                for (int reg = 0; reg < 4; ++reg) {
                    int row = rt * 16 + lg * 4 + reg;
                    TOPV[w][row][0] = v1[rt][reg];
                    TOPV[w][row][1] = __int_as_float(k1r[rt][reg]);
                    TOPV[w][row][2] = v2[rt][reg];
                }
        }
    }
    __syncthreads();

    // ---- merge 4 wave candidates; idx out, flag, lvq = ||enc||^2 + dd_min ----
    if (t < 64) {
        float v1 = 1e30f, v2 = 1e30f; int k1 = 0;
#pragma unroll
        for (int ww = 0; ww < 4; ++ww) {
            float ov1 = TOPV[ww][t][0];
            int ok1 = __float_as_int(TOPV[ww][t][1]);
            float ov2 = TOPV[ww][t][2];
            if (ov1 < v1 || (ov1 == v1 && ok1 < k1)) {
                v2 = fminf(v1, ov2); v1 = ov1; k1 = ok1;
            } else {
                v2 = fminf(v2, ov1);
            }
        }
        int flag = (v2 - v1 >= MARGINF) ? 0 : 1;  // NaN-safe
        IDXR[t] = k1;
        FLAGR[t] = flag;
        int row = row0 + t;
        if (flag)
            atomicOr((unsigned int*)ws + WS_MASK + (row >> 5), 1u << (row & 31));
        out[row] = (float)k1;
        if (!flag) {
            float enc2 = ENC2W[0 * 64 + t] + ENC2W[1 * 64 + t] +
                         ENC2W[2 * 64 + t] + ENC2W[3 * 64 + t];
            lvq = enc2 + v1;
        }
    }
    __syncthreads();

    // ---- gather q (exact fp32), write q_st, hi-only split for decoder ----
    {
        int d = t & 127, rhalf = t >> 7;
#pragma unroll
        for (int e = 0; e < 32; ++e) {
            int r = (e << 1) | rhalf;
            int k1 = IDXR[r];
            float q = emb[(size_t)k1 * 128 + d];
            out[NB + (size_t)(row0 + r) * 128 + d] = q;
            HH[r * 264 + d] = bf16rn(q);
        }
    }

    // ---- decoder (hi-only, 1-term) ----
    mfma_mlp4<4, 4, true, false, 1, false>(D1f, d1b, HH, HL, ENC2W, w, lane);
    mfma_mlp4<4, 8, true, false, 1, false>(D2f, d2b, HH, HL, ENC2W, w, lane);
    __syncthreads();  // dec2 hi ready

    // ---- rec: wave w handles rows w*16..+15 via MFMA (hi-only) ----
    {
        f32x4 racc = (f32x4){0.f, 0.f, 0.f, 0.f};
        for (int c = 0; c < 8; ++c) {
            const int boff = c * 32 + lg * 8;
            short8v bh = *(const short8v*)&HH[(w * 16 + lc) * 264 + boff];
            int fi = (c * 2) * 64 + lane;
            short8v ah = RWf[fi];
            racc = __builtin_amdgcn_mfma_f32_16x16x32_bf16(ah, bh, racc, 0, 0, 0);
        }
        int r = w * 16 + lc;
#pragma unroll
        for (int reg = 0; reg < 4; ++reg) {
            int j = lg * 4 + reg;
            if (j < 6) {
                float rec = tanhf(racc[reg] + rb[j]);
                float df = rec - AT[r * 6 + j];
                if (!FLAGR[r]) lrec += df * df;
            }
        }
    }

    // ---- block loss reduction -> hashed fp64 slots ----
#pragma unroll
    for (int m = 1; m < 64; m <<= 1) {
        lvq += __shfl_xor(lvq, m);
        lrec += __shfl_xor(lrec, m);
    }
    if ((t & 63) == 0) { RED[t >> 6] = lvq; RED[4 + (t >> 6)] = lrec; }
    __syncthreads();
    if (t == 0) {
        int slot = blockIdx.x & 63;
        atomicAdd((double*)ws + slot, (double)((RED[0] + RED[1]) + (RED[2] + RED[3])));
        atomicAdd((double*)ws + 64 + slot, (double)((RED[4] + RED[5]) + (RED[6] + RED[7])));
    }
}

// ---------------- fp64 repair of ambiguous rows (256 blocks, stride over words) ----------------
__global__ __launch_bounds__(256) void vqvae_fix(
    const float* __restrict__ action,
    const float* __restrict__ w1, const float* __restrict__ b1,
    const float* __restrict__ w2, const float* __restrict__ b2,
    const float* __restrict__ w3, const float* __restrict__ b3,
    const float* __restrict__ emb,
    const float* __restrict__ d1w, const float* __restrict__ d1b,
    const float* __restrict__ d2w, const float* __restrict__ d2b,
    const float* __restrict__ rw, const float* __restrict__ rb,
    float* __restrict__ out, float* __restrict__ ws)
{
    __shared__ double H1[256];
    __shared__ double H2[256];
    __shared__ double ENC[128];
    __shared__ double QD[128];
    __shared__ double SRED[256];
    __shared__ int SK[256];
    __shared__ double SA[6];

    const int t = threadIdx.x;

    for (int widx = blockIdx.x; widx < WS_MASKW; widx += gridDim.x) {
        const unsigned int word = ((const unsigned int*)ws)[WS_MASK + widx];
        if (word == 0u) continue;  // uniform across block

        for (int bit = 0; bit < 32; ++bit) {
            if (!(word & (1u << bit))) continue;
            const int row = (widx << 5) + bit;

            if (t < 6) SA[t] = (double)action[(size_t)row * 6 + t];
            __syncthreads();
            {
                double a = (double)b1[t];
#pragma unroll
                for (int i = 0; i < 6; ++i) a += (double)w1[t * 6 + i] * SA[i];
                H1[t] = a > 0.0 ? a : 0.0;
            }
            __syncthreads();
            {
                const float* w = w2 + (size_t)t * 256;
                double a0 = 0, a1 = 0, a2 = 0, a3 = 0;
                for (int i = 0; i < 256; i += 4) {
                    a0 += (double)w[i] * H1[i];     a1 += (double)w[i + 1] * H1[i + 1];
                    a2 += (double)w[i + 2] * H1[i + 2]; a3 += (double)w[i + 3] * H1[i + 3];
                }
                double a = (double)b2[t] + a0 + a1 + a2 + a3;
                H2[t] = a > 0.0 ? a : 0.0;
            }
            __syncthreads();
            if (t < 128) {
                const float* w = w3 + (size_t)t * 256;
                double a0 = 0, a1 = 0, a2 = 0, a3 = 0;
                for (int i = 0; i < 256; i += 4) {
                    a0 += (double)w[i] * H2[i];     a1 += (double)w[i + 1] * H2[i + 1];
                    a2 += (double)w[i + 2] * H2[i + 2]; a3 += (double)w[i + 3] * H2[i + 3];
                }
                ENC[t] = (double)b3[t] + a0 + a1 + a2 + a3;
            }
            __syncthreads();
            double best = 1e300; int bk = 0;
#pragma unroll
            for (int kk = 0; kk < 2; ++kk) {
                int k = t + kk * 256;
                const float* e = emb + (size_t)k * 128;
                double s0 = 0, s1 = 0;
                for (int d = 0; d < 128; d += 2) {
                    double df0 = ENC[d] - (double)e[d];
                    double df1 = ENC[d + 1] - (double)e[d + 1];
                    s0 += df0 * df0; s1 += df1 * df1;
                }
                double s = s0 + s1;
                if (s < best) { best = s; bk = k; }
            }
            SRED[t] = best; SK[t] = bk;
            __syncthreads();
            for (int st = 128; st > 0; st >>= 1) {
                if (t < st) {
                    double ov = SRED[t + st]; int ok = SK[t + st];
                    if (ov < SRED[t] || (ov == SRED[t] && ok < SK[t])) { SRED[t] = ov; SK[t] = ok; }
                }
                __syncthreads();
            }
            const int bestk = SK[0];
            double lv = 0.0;
            if (t < 128) {
                double q = (double)emb[(size_t)bestk * 128 + t];
                QD[t] = q;
                double df = ENC[t] - q;
                lv = df * df;
                out[NB + (size_t)row * 128 + t] = (float)q;
            }
            if (t == 0) out[row] = (float)bestk;
            __syncthreads();
            {
                const float* w = d1w + (size_t)t * 128;
                double a0 = 0, a1 = 0;
                for (int i = 0; i < 128; i += 2) {
                    a0 += (double)w[i] * QD[i]; a1 += (double)w[i + 1] * QD[i + 1];
                }
                double a = (double)d1b[t] + a0 + a1;
                H1[t] = a > 0.0 ? a : 0.0;
            }
            __syncthreads();
            {
                const float* w = d2w + (size_t)t * 256;
                double a0 = 0, a1 = 0, a2 = 0, a3 = 0;
                for (int i = 0; i < 256; i += 4) {
                    a0 += (double)w[i] * H1[i];     a1 += (double)w[i + 1] * H1[i + 1];
                    a2 += (double)w[i + 2] * H1[i + 2]; a3 += (double)w[i + 3] * H1[i + 3];
                }
                double a = (double)d2b[t] + a0 + a1 + a2 + a3;
                H2[t] = a > 0.0 ? a : 0.0;
            }
            __syncthreads();
            double lr = 0.0;
            if (t < 6) {
                const float* w = rw + (size_t)t * 256;
                double a0 = 0, a1 = 0;
                for (int i = 0; i < 256; i += 2) {
                    a0 += (double)w[i] * H2[i]; a1 += (double)w[i + 1] * H2[i + 1];
                }
                double rec = tanh((double)rb[t] + a0 + a1);
                double df = rec - SA[t];
                lr = df * df;
            }
            SRED[t] = lv;
            __syncthreads();
            for (int st = 128; st > 0; st >>= 1) {
                if (t < st) SRED[t] += SRED[t + st];
                __syncthreads();
            }
            if (t == 0) atomicAdd((double*)ws + 0, SRED[0]);
            if (t < 6) atomicAdd((double*)ws + 64, lr);
            __syncthreads();
        }
    }
}

__global__ void vqvae_fin(const float* __restrict__ ws, float* __restrict__ out) {
    if (threadIdx.x == 0 && blockIdx.x == 0) {
        const double* D = (const double*)ws;
        double sv = 0.0, sr = 0.0;
        for (int i = 0; i < 64; ++i) { sv += D[i]; sr += D[64 + i]; }
        double loss = sr / ((double)NB * 6.0) + 1.25 * (sv / ((double)NB * 128.0));
        out[(size_t)NB * 129] = (float)loss;
    }
}

// ---------------- fp32 fallback (only if ws too small for splits) ----------------
static __device__ __forceinline__ void gemm_out256(
    const float* __restrict__ W, const float* __restrict__ bias, int IN,
    const float* __restrict__ hin, float* __restrict__ hout,
    float* __restrict__ WC, int t, int tx, int r0, bool do_relu)
{
    float acc[2][4][4];
#pragma unroll
    for (int g = 0; g < 2; ++g)
#pragma unroll
        for (int a = 0; a < 4; ++a)
#pragma unroll
            for (int b = 0; b < 4; ++b) acc[g][a][b] = 0.f;
    float4 pa = *(const float4*)(W + (size_t)t * IN);
    float4 pb = *(const float4*)(W + (size_t)t * IN + 4);
    for (int i0 = 0; i0 < IN; i0 += 8) {
        __syncthreads();
        WC[0 * 256 + t] = pa.x; WC[1 * 256 + t] = pa.y;
        WC[2 * 256 + t] = pa.z; WC[3 * 256 + t] = pa.w;
        WC[4 * 256 + t] = pb.x; WC[5 * 256 + t] = pb.y;
        WC[6 * 256 + t] = pb.z; WC[7 * 256 + t] = pb.w;
        __syncthreads();
        if (i0 + 8 < IN) {
            pa = *(const float4*)(W + (size_t)t * IN + i0 + 8);
            pb = *(const float4*)(W + (size_t)t * IN + i0 + 12);
        }
#pragma unroll
        for (int i = 0; i < 8; ++i) {
            int row = i0 + i;
            float4 h = *(const float4*)&hin[row * 32 + (r0 ^ SWC(row))];
            float4 w0 = *(const float4*)&WC[i * 256 + 4 * tx];
            float4 w1v = *(const float4*)&WC[i * 256 + 128 + 4 * tx];
            float wv0[4] = {w0.x, w0.y, w0.z, w0.w};
            float wv1[4] = {w1v.x, w1v.y, w1v.z, w1v.w};
            float hv[4] = {h.x, h.y, h.z, h.w};
#pragma unroll
            for (int a = 0; a < 4; ++a)
#pragma unroll
                for (int b = 0; b < 4; ++b) {
                    acc[0][a][b] += wv0[a] * hv[b];
                    acc[1][a][b] += wv1[a] * hv[b];
                }
        }
    }
#pragma unroll
    for (int g = 0; g < 2; ++g)
#pragma unroll
        for (int a = 0; a < 4; ++a) {
            int j = g * 128 + 4 * tx + a;
            float bj = bias[j];
            float4 v;
            v.x = acc[g][a][0] + bj; v.y = acc[g][a][1] + bj;
            v.z = acc[g][a][2] + bj; v.w = acc[g][a][3] + bj;
            if (do_relu) {
                v.x = fmaxf(v.x, 0.f); v.y = fmaxf(v.y, 0.f);
                v.z = fmaxf(v.z, 0.f); v.w = fmaxf(v.w, 0.f);
            }
            *(float4*)&hout[j * 32 + (r0 ^ SWC(j))] = v;
        }
    __syncthreads();
}

__global__ __launch_bounds__(256, 2) void vqvae_main_fp32(
    const float* __restrict__ action,
    const float* __restrict__ w1, const float* __restrict__ b1,
    const float* __restrict__ w2, const float* __restrict__ b2,
    const float* __restrict__ w3, const float* __restrict__ b3,
    const float* __restrict__ emb,
    const float* __restrict__ d1w, const float* __restrict__ d1b,
    const float* __restrict__ d2w, const float* __restrict__ d2b,
    const float* __restrict__ rw, const float* __restrict__ rb,
    float* __restrict__ out, float* __restrict__ ws)
{
    __shared__ float X[256 * 32];
    __shared__ float Y[256 * 32];
    __shared__ float WC[2048];
    __shared__ float AT[6 * 32];
    __shared__ int IDXR[32];
    __shared__ int FLAGR[32];
    __shared__ float RED[8];

    const int t = threadIdx.x;
    const int tx = t & 31, ty = t >> 5;
    const int r0 = ty * 4;
    const int row0 = blockIdx.x * 32;

    if (t < 192) {
        int r = t / 6, i = t - r * 6;
        AT[i * 32 + r] = action[(size_t)row0 * 6 + t];
    }
    __syncthreads();
    {
#pragma unroll
        for (int i = 0; i < 6; ++i) WC[i * 256 + t] = w1[t * 6 + i];
        __syncthreads();
        float acc[2][4][4];
#pragma unroll
        for (int g = 0; g < 2; ++g)
#pragma unroll
            for (int a = 0; a < 4; ++a)
#pragma unroll
                for (int b = 0; b < 4; ++b) acc[g][a][b] = 0.f;
#pragma unroll
        for (int i = 0; i < 6; ++i) {
            float4 h = *(const float4*)&AT[i * 32 + r0];
            float4 w0 = *(const float4*)&WC[i * 256 + 4 * tx];
            float4 w1v = *(const float4*)&WC[i * 256 + 128 + 4 * tx];
            float wv0[4] = {w0.x, w0.y, w0.z, w0.w};
            float wv1[4] = {w1v.x, w1v.y, w1v.z, w1v.w};
            float hv[4] = {h.x, h.y, h.z, h.w};
#pragma unroll
            for (int a = 0; a < 4; ++a)
#pragma unroll
                for (int b = 0; b < 4; ++b) {
                    acc[0][a][b] += wv0[a] * hv[b];
                    acc[1][a][b] += wv1[a] * hv[b];
                }
        }
#pragma unroll
        for (int g = 0; g < 2; ++g)
#pragma unroll
            for (int a = 0; a < 4; ++a) {
                int j = g * 128 + 4 * tx + a;
                float bj = b1[j];
                float4 v;
                v.x = fmaxf(acc[g][a][0] + bj, 0.f);
                v.y = fmaxf(acc[g][a][1] + bj, 0.f);
                v.z = fmaxf(acc[g][a][2] + bj, 0.f);
                v.w = fmaxf(acc[g][a][3] + bj, 0.f);
                *(float4*)&X[j * 32 + (r0 ^ SWC(j))] = v;
            }
        __syncthreads();
    }
    gemm_out256(w2, b2, 256, X, Y, WC, t, tx, r0, true);
    {
        float acc[4][4];
#pragma unroll
        for (int a = 0; a < 4; ++a)
#pragma unroll
            for (int b = 0; b < 4; ++b) acc[a][b] = 0.f;
        float4 pa, pb;
        if (t < 128) {
            pa = *(const float4*)(w3 + (size_t)t * 256);
            pb = *(const float4*)(w3 + (size_t)t * 256 + 4);
        }
        for (int i0 = 0; i0 < 256; i0 += 8) {
            __syncthreads();
            if (t < 128) {
                WC[0 * 128 + t] = pa.x; WC[1 * 128 + t] = pa.y;
                WC[2 * 128 + t] = pa.z; WC[3 * 128 + t] = pa.w;
                WC[4 * 128 + t] = pb.x; WC[5 * 128 + t] = pb.y;
                WC[6 * 128 + t] = pb.z; WC[7 * 128 + t] = pb.w;
            }
            __syncthreads();
            if (t < 128 && i0 + 8 < 256) {
                pa = *(const float4*)(w3 + (size_t)t * 256 + i0 + 8);
                pb = *(const float4*)(w3 + (size_t)t * 256 + i0 + 12);
            }
#pragma unroll
            for (int i = 0; i < 8; ++i) {
                int row = i0 + i;
                float4 h = *(const float4*)&Y[row * 32 + (r0 ^ SWC(row))];
                float4 w0 = *(const float4*)&WC[i * 128 + 4 * tx];
                float wv[4] = {w0.x, w0.y, w0.z, w0.w};
                float hv[4] = {h.x, h.y, h.z, h.w};
#pragma unroll
                for (int a = 0; a < 4; ++a)
#pragma unroll
                    for (int b = 0; b < 4; ++b) acc[a][b] += wv[a] * hv[b];
            }
        }
#pragma unroll
        for (int a = 0; a < 4; ++a) {
            int j = 4 * tx + a;
            float bj = b3[j];
            float4 v;
            v.x = acc[a][0] + bj; v.y = acc[a][1] + bj;
            v.z = acc[a][2] + bj; v.w = acc[a][3] + bj;
            *(float4*)&X[j * 32 + (r0 ^ SWC(j))] = v;
        }
        __syncthreads();
    }
    {
        float bv1[4], bv2[4];
        int bk1[4];
        float acc[4][4][4];
#pragma unroll
        for (int p = 0; p < 4; ++p)
#pragma unroll
            for (int a = 0; a < 4; ++a)
#pragma unroll
                for (int b = 0; b < 4; ++b) acc[p][a][b] = 0.f;
        float4 qa = *(const float4*)(emb + (size_t)t * 128);
        float4 qb = *(const float4*)(emb + (size_t)(t + 256) * 128);
        for (int d0 = 0; d0 < 128; d0 += 4) {
            __syncthreads();
            WC[0 * 512 + t] = qa.x; WC[1 * 512 + t] = qa.y;
            WC[2 * 512 + t] = qa.z; WC[3 * 512 + t] = qa.w;
            WC[0 * 512 + 256 + t] = qb.x; WC[1 * 512 + 256 + t] = qb.y;
            WC[2 * 512 + 256 + t] = qb.z; WC[3 * 512 + 256 + t] = qb.w;
            __syncthreads();
            if (d0 + 4 < 128) {
                qa = *(const float4*)(emb + (size_t)t * 128 + d0 + 4);
                qb = *(const float4*)(emb + (size_t)(t + 256) * 128 + d0 + 4);
            }
#pragma unroll
            for (int i = 0; i < 4; ++i) {
                int row = d0 + i;
                float4 h = *(const float4*)&X[row * 32 + (r0 ^ SWC(row))];
                float hv[4] = {h.x, h.y, h.z, h.w};
#pragma unroll
                for (int p = 0; p < 4; ++p) {
                    float4 w0 = *(const float4*)&WC[i * 512 + p * 128 + 4 * tx];
                    float wv[4] = {w0.x, w0.y, w0.z, w0.w};
#pragma unroll
                    for (int a = 0; a < 4; ++a)
#pragma unroll
                        for (int b = 0; b < 4; ++b) acc[p][a][b] += wv[a] * hv[b];
                }
            }
        }
#pragma unroll
        for (int b = 0; b < 4; ++b) { bv1[b] = 1e30f; bv2[b] = 1e30f; bk1[b] = 0; }
#pragma unroll
        for (int p = 0; p < 4; ++p)
#pragma unroll
            for (int a = 0; a < 4; ++a) {
                int k = p * 128 + 4 * tx + a;
                float ek = ws[WS_E2 + k];
#pragma unroll
                for (int b = 0; b < 4; ++b) {
                    float dd = ek - 2.f * acc[p][a][b];
                    if (dd < bv1[b]) { bv2[b] = bv1[b]; bv1[b] = dd; bk1[b] = k; }
                    else if (dd < bv2[b]) bv2[b] = dd;
                }
            }
#pragma unroll
        for (int m = 1; m < 32; m <<= 1) {
#pragma unroll
            for (int b = 0; b < 4; ++b) {
                float ov1 = __shfl_xor(bv1[b], m);
                int ok1 = __shfl_xor(bk1[b], m);
                float ov2 = __shfl_xor(bv2[b], m);
                if (ov1 < bv1[b] || (ov1 == bv1[b] && ok1 < bk1[b])) {
                    bv2[b] = fminf(bv1[b], ov2);
                    bv1[b] = ov1; bk1[b] = ok1;
                } else {
                    bv2[b] = fminf(bv2[b], ov1);
                }
            }
        }
        if (tx == 0) {
#pragma unroll
            for (int b = 0; b < 4; ++b) {
                IDXR[r0 + b] = bk1[b];
                FLAGR[r0 + b] = (bv2[b] - bv1[b] >= MARGINF) ? 0 : 1;
            }
        }
    }
    __syncthreads();
    if (t < 32) {
        int row = row0 + t;
        if (FLAGR[t])
            atomicOr((unsigned int*)ws + WS_MASK + (row >> 5), 1u << (row & 31));
        out[row] = (float)IDXR[t];
    }
    float lvq = 0.f, lrec = 0.f;
    {
        int d = t & 127, rq = t >> 7;
        int cd = SWC(d);
#pragma unroll
        for (int e = 0; e < 4; ++e) {
            int rr = (rq + 2 * e) * 4;
            float4 en = *(const float4*)&X[d * 32 + (rr ^ cd)];
            float q0 = emb[(size_t)IDXR[rr + 0] * 128 + d];
            float q1 = emb[(size_t)IDXR[rr + 1] * 128 + d];
            float q2 = emb[(size_t)IDXR[rr + 2] * 128 + d];
            float q3 = emb[(size_t)IDXR[rr + 3] * 128 + d];
            float4 qv; qv.x = q0; qv.y = q1; qv.z = q2; qv.w = q3;
            *(float4*)&X[(128 + d) * 32 + (rr ^ cd)] = qv;
            if (!FLAGR[rr + 0]) lvq += (en.x - q0) * (en.x - q0);
            if (!FLAGR[rr + 1]) lvq += (en.y - q1) * (en.y - q1);
            if (!FLAGR[rr + 2]) lvq += (en.z - q2) * (en.z - q2);
            if (!FLAGR[rr + 3]) lvq += (en.w - q3) * (en.w - q3);
            out[NB + (size_t)(row0 + rr + 0) * 128 + d] = q0;
            out[NB + (size_t)(row0 + rr + 1) * 128 + d] = q1;
            out[NB + (size_t)(row0 + rr + 2) * 128 + d] = q2;
            out[NB + (size_t)(row0 + rr + 3) * 128 + d] = q3;
        }
    }
    __syncthreads();
    gemm_out256(d1w, d1b, 128, X + 128 * 32, Y, WC, t, tx, r0, true);
    gemm_out256(d2w, d2b, 256, Y, X, WC, t, tx, r0, true);
    if (t < 192) {
        int jj = t >> 5, r = t & 31;
        const float* wr = rw + jj * 256;
        float a0 = 0.f, a1 = 0.f, a2 = 0.f, a3 = 0.f;
        for (int i = 0; i < 256; i += 4) {
            a0 += wr[i] * X[i * 32 + (r ^ SWC(i))];
            a1 += wr[i + 1] * X[(i + 1) * 32 + (r ^ SWC(i + 1))];
            a2 += wr[i + 2] * X[(i + 2) * 32 + (r ^ SWC(i + 2))];
            a3 += wr[i + 3] * X[(i + 3) * 32 + (r ^ SWC(i + 3))];
        }
        float rec = tanhf(rb[jj] + (a0 + a1) + (a2 + a3));
        float df = rec - AT[jj * 32 + r];
        if (!FLAGR[r]) lrec = df * df;
    }
#pragma unroll
    for (int m = 1; m < 64; m <<= 1) {
        lvq += __shfl_xor(lvq, m);
        lrec += __shfl_xor(lrec, m);
    }
    if ((t & 63) == 0) { RED[t >> 6] = lvq; RED[4 + (t >> 6)] = lrec; }
    __syncthreads();
    if (t == 0) {
        int slot = blockIdx.x & 63;
        atomicAdd((double*)ws + slot, (double)((RED[0] + RED[1]) + (RED[2] + RED[3])));
        atomicAdd((double*)ws + 64 + slot, (double)((RED[4] + RED[5]) + (RED[6] + RED[7])));
    }
}

extern "C" void kernel_launch(void* const* d_in, const int* in_sizes, int n_in,
                              void* d_out, int out_size, void* d_ws, size_t ws_size,
                              hipStream_t stream) {
    const float* action = (const float*)d_in[0];
    const float* w1 = (const float*)d_in[1];
    const float* b1 = (const float*)d_in[2];
    const float* w2 = (const float*)d_in[3];
    const float* b2 = (const float*)d_in[4];
    const float* w3 = (const float*)d_in[5];
    const float* b3 = (const float*)d_in[6];
    const float* emb = (const float*)d_in[7];
    const float* d1w = (const float*)d_in[8];
    const float* d1b = (const float*)d_in[9];
    const float* d2w = (const float*)d_in[10];
    const float* d2b = (const float*)d_in[11];
    const float* rw = (const float*)d_in[12];
    const float* rb = (const float*)d_in[13];
    float* out = (float*)d_out;
    float* ws = (float*)d_ws;

    const size_t need_mfma = (size_t)WS_BASE_BYTES + (size_t)SPLIT_TOTAL * 2;
    const int use_mfma = (ws_size >= need_mfma) ? 1 : 0;
    const int dyn_lds = 64 * 264 * 2 * 2;  // 67584 B

    size_t clear = ws_size < (size_t)WS_BASE_BYTES ? ws_size : (size_t)WS_BASE_BYTES;
    hipMemsetAsync(d_ws, 0, clear, stream);

    prep_kernel<<<1043, 256, 0, stream>>>(w2, w3, emb, d1w, d2w, rw, ws, use_mfma);
    if (use_mfma) {
        hipFuncSetAttribute((const void*)vqvae_main_mfma,
                            hipFuncAttributeMaxDynamicSharedMemorySize, dyn_lds);
        vqvae_main_mfma<<<NB / 64, 256, dyn_lds, stream>>>(action, w1, b1, b2, b3, emb,
                                                           d1b, d2b, rb, out, ws);
    } else {
        vqvae_main_fp32<<<NB / 32, 256, 0, stream>>>(action, w1, b1, w2, b2, w3, b3, emb,
                                                     d1w, d1b, d2w, d2b, rw, rb, out, ws);
    }
    vqvae_fix<<<256, 256, 0, stream>>>(action, w1, b1, w2, b2, w3, b3, emb,
                                       d1w, d1b, d2w, d2b, rw, rb, out, ws);
    vqvae_fin<<<1, 64, 0, stream>>>(ws, out);
}